// Round 1
// baseline (2870.356 us; speedup 1.0000x reference)
//
#include <hip/hip_runtime.h>

// BinaryConnectNet forward. Correctness-first round.
// Stage 1 (continuous pre-sign) in fp64; stage 2 exact int; fc1 fp64 accumulate.

__device__ __forceinline__ int fsign(float v)  { return (v > 0.f) - (v < 0.f); }
__device__ __forceinline__ int dsign(double v) { return (v > 0.0) - (v < 0.0); }

// -------- Kernel 1: conv1 dw(3x3,g=3) + pw(1x1 3->128) + sign + maxpool2
// -> pooled1 [1024,128,16,16] int8.  One block per sample n; thread = (py,px).
__global__ void k1_conv1(const float* __restrict__ x,
                         const float* __restrict__ w1dw, const float* __restrict__ b1dw,
                         const float* __restrict__ w1pw, const float* __restrict__ b1pw,
                         signed char* __restrict__ pooled1)
{
    __shared__ float sdw[27], sbdw[3], spw[384], sbpw[128];
    int t = threadIdx.x;
    if (t < 27) sdw[t] = (float)fsign(w1dw[t]);
    if (t < 3)  sbdw[t] = (float)fsign(b1dw[t]);
    for (int i = t; i < 384; i += 256) spw[i] = (float)fsign(w1pw[i]);
    if (t < 128) sbpw[t] = (float)fsign(b1pw[t]);
    __syncthreads();

    int g  = blockIdx.x * 256 + t;
    int px = g & 15, py = (g >> 4) & 15, n = g >> 8;

    // depthwise 3x3 (fp64) at the 4 sub-positions of this pooled cell
    double h[3][4];
    const float* xb = x + (size_t)n * 3 * 1024;
    #pragma unroll
    for (int c = 0; c < 3; c++) {
        const float* xc = xb + c * 1024;
        #pragma unroll
        for (int dy = 0; dy < 2; dy++)
        #pragma unroll
        for (int dx = 0; dx < 2; dx++) {
            int y = 2 * py + dy, xx = 2 * px + dx;
            double acc = (double)sbdw[c];
            #pragma unroll
            for (int ky = 0; ky < 3; ky++) {
                int yy = y + ky - 1;
                if (yy < 0 || yy > 31) continue;
                #pragma unroll
                for (int kx = 0; kx < 3; kx++) {
                    int xxx = xx + kx - 1;
                    if (xxx < 0 || xxx > 31) continue;
                    acc += (double)sdw[c * 9 + ky * 3 + kx] * (double)xc[yy * 32 + xxx];
                }
            }
            h[c][dy * 2 + dx] = acc;
        }
    }

    signed char* outb = pooled1 + (size_t)n * 128 * 256 + py * 16 + px;
    for (int o = 0; o < 128; o++) {
        double s0 = (double)spw[o * 3 + 0];
        double s1 = (double)spw[o * 3 + 1];
        double s2 = (double)spw[o * 3 + 2];
        double sb = (double)sbpw[o];
        int mx = -2;
        #pragma unroll
        for (int q = 0; q < 4; q++) {
            double p = s0 * h[0][q] + s1 * h[1][q] + s2 * h[2][q] + sb;
            int s = dsign(p);
            mx = s > mx ? s : mx;
        }
        outb[(size_t)o * 256] = (signed char)mx;
    }
}

// -------- Kernel 2: conv2 dw(3x3, g=128) on int8 signs -> dw2 [1024,128,16,16] int8
// One block per (n,c) slab; thread = (y,x). Exact integers in [-10,10].
__global__ void k2_dw2(const signed char* __restrict__ pooled1,
                       const float* __restrict__ w2dw, const float* __restrict__ b2dw,
                       signed char* __restrict__ dw2)
{
    int g = blockIdx.x * 256 + threadIdx.x;
    int xx = g & 15, y = (g >> 4) & 15;
    int nc = g >> 8;             // n*128 + c
    int c = nc & 127;

    int sw[9];
    #pragma unroll
    for (int i = 0; i < 9; i++) sw[i] = fsign(w2dw[c * 9 + i]);
    int acc = fsign(b2dw[c]);

    const signed char* p = pooled1 + (size_t)nc * 256;
    #pragma unroll
    for (int ky = 0; ky < 3; ky++) {
        int yy = y + ky - 1;
        if (yy < 0 || yy > 15) continue;
        #pragma unroll
        for (int kx = 0; kx < 3; kx++) {
            int xxx = xx + kx - 1;
            if (xxx < 0 || xxx > 15) continue;
            acc += sw[ky * 3 + kx] * (int)p[yy * 16 + xxx];
        }
    }
    dw2[(size_t)g] = (signed char)acc;
}

// -------- Kernel 3: conv2 pw(1x1 128->256) + sign + maxpool2 -> hT [16384 x 1024] int8
// Exact int32. hT is k-major (k = o*64+py*8+px) so fc1 reads are coalesced in n.
__global__ void k3_pw2(const signed char* __restrict__ dw2,
                       const float* __restrict__ w2pw, const float* __restrict__ b2pw,
                       signed char* __restrict__ hT)
{
    int g = blockIdx.x * 256 + threadIdx.x;           // 1024*256*64 threads
    int px = g & 7, py = (g >> 3) & 7, o = (g >> 6) & 255, n = g >> 14;

    const signed char* db = dw2 + (size_t)n * 128 * 256;
    int b = fsign(b2pw[o]);
    int p0 = b, p1 = b, p2 = b, p3 = b;
    int base = (2 * py) * 16 + 2 * px;
    for (int c = 0; c < 128; c++) {
        int sw = fsign(w2pw[o * 128 + c]);
        const signed char* d = db + c * 256 + base;
        p0 += sw * (int)d[0];
        p1 += sw * (int)d[1];
        p2 += sw * (int)d[16];
        p3 += sw * (int)d[17];
    }
    int s0 = (p0 > 0) - (p0 < 0), s1 = (p1 > 0) - (p1 < 0);
    int s2 = (p2 > 0) - (p2 < 0), s3 = (p3 > 0) - (p3 < 0);
    int mx = max(max(s0, s1), max(s2, s3));
    int k = o * 64 + py * 8 + px;
    hT[(size_t)k * 1024 + n] = (signed char)mx;
}

// -------- Kernel 4: fc1 (h[1024x16384] @ fc1_w^T[16384x1024]) fp64 accumulate + sign
// -> hs [1024 n x 1024 j] int8. Block = 2 j-rows x 1024 n (4 n per thread).
__global__ void k4_fc1(const signed char* __restrict__ hT,
                       const float* __restrict__ fc1w, const float* __restrict__ fc1b,
                       signed char* __restrict__ hs)
{
    int j0 = blockIdx.x * 2;
    int n0 = threadIdx.x * 4;
    double acc[2][4];
    #pragma unroll
    for (int a = 0; a < 2; a++)
        #pragma unroll
        for (int b = 0; b < 4; b++) acc[a][b] = 0.0;

    const float* w0p = fc1w + (size_t)(j0 + 0) * 16384;
    const float* w1p = fc1w + (size_t)(j0 + 1) * 16384;
    for (int k = 0; k < 16384; k++) {
        int hw = *reinterpret_cast<const int*>(hT + (size_t)k * 1024 + n0);
        double h0 = (double)((int)(signed char)(hw & 0xff));
        double h1 = (double)((int)(signed char)((hw >> 8) & 0xff));
        double h2 = (double)((int)(signed char)((hw >> 16) & 0xff));
        double h3 = (double)((int)(signed char)(hw >> 24));
        double w0 = (double)w0p[k];
        double w1 = (double)w1p[k];
        acc[0][0] += w0 * h0; acc[0][1] += w0 * h1; acc[0][2] += w0 * h2; acc[0][3] += w0 * h3;
        acc[1][0] += w1 * h0; acc[1][1] += w1 * h1; acc[1][2] += w1 * h2; acc[1][3] += w1 * h3;
    }

    #pragma unroll
    for (int a = 0; a < 2; a++) {
        double bj = (double)fc1b[j0 + a];
        #pragma unroll
        for (int b = 0; b < 4; b++) {
            double p = acc[a][b] + bj;
            hs[(size_t)(n0 + b) * 1024 + (j0 + a)] = (signed char)((p > 0.0) - (p < 0.0));
        }
    }
}

// -------- Kernel 5: fc2 (1024x1024 -> 10), fp64 accumulate, write fp32 out [1024,10]
__global__ void k5_fc2(const signed char* __restrict__ hs,
                       const float* __restrict__ fc2w, const float* __restrict__ fc2b,
                       float* __restrict__ out)
{
    int n = blockIdx.x * 256 + threadIdx.x;
    if (n >= 1024) return;
    double acc[10];
    #pragma unroll
    for (int m = 0; m < 10; m++) acc[m] = (double)fc2b[m];
    const signed char* hr = hs + (size_t)n * 1024;
    for (int j = 0; j < 1024; j++) {
        double dh = (double)(int)hr[j];
        #pragma unroll
        for (int m = 0; m < 10; m++) acc[m] += dh * (double)fc2w[m * 1024 + j];
    }
    #pragma unroll
    for (int m = 0; m < 10; m++) out[n * 10 + m] = (float)acc[m];
}

extern "C" void kernel_launch(void* const* d_in, const int* in_sizes, int n_in,
                              void* d_out, int out_size, void* d_ws, size_t ws_size,
                              hipStream_t stream)
{
    const float* x    = (const float*)d_in[0];
    const float* w1dw = (const float*)d_in[1];
    const float* b1dw = (const float*)d_in[2];
    const float* w1pw = (const float*)d_in[3];
    const float* b1pw = (const float*)d_in[4];
    const float* w2dw = (const float*)d_in[5];
    const float* b2dw = (const float*)d_in[6];
    const float* w2pw = (const float*)d_in[7];
    const float* b2pw = (const float*)d_in[8];
    const float* fc1w = (const float*)d_in[9];
    const float* fc1b = (const float*)d_in[10];
    const float* fc2w = (const float*)d_in[11];
    const float* fc2b = (const float*)d_in[12];
    float* out = (float*)d_out;

    // workspace layout (needs 85 MB)
    char* ws = (char*)d_ws;
    signed char* pooled1 = (signed char*)(ws);                       // 33,554,432
    signed char* dw2     = (signed char*)(ws + 33554432);            // 33,554,432
    signed char* hT      = (signed char*)(ws + 67108864);            // 16,777,216
    signed char* hs      = (signed char*)(ws + 83886080);            //  1,048,576

    hipLaunchKernelGGL(k1_conv1, dim3(1024),   dim3(256), 0, stream,
                       x, w1dw, b1dw, w1pw, b1pw, pooled1);
    hipLaunchKernelGGL(k2_dw2,   dim3(131072), dim3(256), 0, stream,
                       pooled1, w2dw, b2dw, dw2);
    hipLaunchKernelGGL(k3_pw2,   dim3(65536),  dim3(256), 0, stream,
                       dw2, w2pw, b2pw, hT);
    hipLaunchKernelGGL(k4_fc1,   dim3(512),    dim3(256), 0, stream,
                       hT, fc1w, fc1b, hs);
    hipLaunchKernelGGL(k5_fc2,   dim3(4),      dim3(256), 0, stream,
                       hs, fc2w, fc2b, out);
}

// Round 2
// 1430.211 us; speedup vs baseline: 2.0069x; 2.0069x over previous
//
#include <hip/hip_runtime.h>

// BinaryConnectNet forward.
// R2: fc1 via exact int8-limb MFMA GEMM (4 limbs radix-128 on a 2^-32 grid).

__device__ __forceinline__ int fsign(float v)  { return (v > 0.f) - (v < 0.f); }
__device__ __forceinline__ int dsign(double v) { return (v > 0.0) - (v < 0.0); }

typedef int v4i __attribute__((ext_vector_type(4)));

// -------- Kernel 1: conv1 dw(3x3,g=3) + pw(1x1 3->128) + sign + maxpool2
// -> pooled1 [1024,128,16,16] int8.
__global__ void k1_conv1(const float* __restrict__ x,
                         const float* __restrict__ w1dw, const float* __restrict__ b1dw,
                         const float* __restrict__ w1pw, const float* __restrict__ b1pw,
                         signed char* __restrict__ pooled1)
{
    __shared__ float sdw[27], sbdw[3], spw[384], sbpw[128];
    int t = threadIdx.x;
    if (t < 27) sdw[t] = (float)fsign(w1dw[t]);
    if (t < 3)  sbdw[t] = (float)fsign(b1dw[t]);
    for (int i = t; i < 384; i += 256) spw[i] = (float)fsign(w1pw[i]);
    if (t < 128) sbpw[t] = (float)fsign(b1pw[t]);
    __syncthreads();

    int g  = blockIdx.x * 256 + t;
    int px = g & 15, py = (g >> 4) & 15, n = g >> 8;

    double h[3][4];
    const float* xb = x + (size_t)n * 3 * 1024;
    #pragma unroll
    for (int c = 0; c < 3; c++) {
        const float* xc = xb + c * 1024;
        #pragma unroll
        for (int dy = 0; dy < 2; dy++)
        #pragma unroll
        for (int dx = 0; dx < 2; dx++) {
            int y = 2 * py + dy, xx = 2 * px + dx;
            double acc = (double)sbdw[c];
            #pragma unroll
            for (int ky = 0; ky < 3; ky++) {
                int yy = y + ky - 1;
                if (yy < 0 || yy > 31) continue;
                #pragma unroll
                for (int kx = 0; kx < 3; kx++) {
                    int xxx = xx + kx - 1;
                    if (xxx < 0 || xxx > 31) continue;
                    acc += (double)sdw[c * 9 + ky * 3 + kx] * (double)xc[yy * 32 + xxx];
                }
            }
            h[c][dy * 2 + dx] = acc;
        }
    }

    signed char* outb = pooled1 + (size_t)n * 128 * 256 + py * 16 + px;
    for (int o = 0; o < 128; o++) {
        double s0 = (double)spw[o * 3 + 0];
        double s1 = (double)spw[o * 3 + 1];
        double s2 = (double)spw[o * 3 + 2];
        double sb = (double)sbpw[o];
        int mx = -2;
        #pragma unroll
        for (int q = 0; q < 4; q++) {
            double p = s0 * h[0][q] + s1 * h[1][q] + s2 * h[2][q] + sb;
            int s = dsign(p);
            mx = s > mx ? s : mx;
        }
        outb[(size_t)o * 256] = (signed char)mx;
    }
}

// -------- Kernel 2: conv2 dw(3x3, g=128) on int8 signs -> dw2 [1024,128,16,16] int8
__global__ void k2_dw2(const signed char* __restrict__ pooled1,
                       const float* __restrict__ w2dw, const float* __restrict__ b2dw,
                       signed char* __restrict__ dw2)
{
    int g = blockIdx.x * 256 + threadIdx.x;
    int xx = g & 15, y = (g >> 4) & 15;
    int nc = g >> 8;
    int c = nc & 127;

    int sw[9];
    #pragma unroll
    for (int i = 0; i < 9; i++) sw[i] = fsign(w2dw[c * 9 + i]);
    int acc = fsign(b2dw[c]);

    const signed char* p = pooled1 + (size_t)nc * 256;
    #pragma unroll
    for (int ky = 0; ky < 3; ky++) {
        int yy = y + ky - 1;
        if (yy < 0 || yy > 15) continue;
        #pragma unroll
        for (int kx = 0; kx < 3; kx++) {
            int xxx = xx + kx - 1;
            if (xxx < 0 || xxx > 15) continue;
            acc += sw[ky * 3 + kx] * (int)p[yy * 16 + xxx];
        }
    }
    dw2[(size_t)g] = (signed char)acc;
}

// -------- Kernel 3: conv2 pw(1x1 128->256) + sign + maxpool2 -> hT2 [1024 n][16384 k] int8
// k = o*64 + py*8 + px (matches reshape order). n-major so fc1 A-frags are k-contiguous.
__global__ void k3_pw2(const signed char* __restrict__ dw2,
                       const float* __restrict__ w2pw, const float* __restrict__ b2pw,
                       signed char* __restrict__ hT2)
{
    int g = blockIdx.x * 256 + threadIdx.x;
    int px = g & 7, py = (g >> 3) & 7, o = (g >> 6) & 255, n = g >> 14;

    const signed char* db = dw2 + (size_t)n * 128 * 256;
    int b = fsign(b2pw[o]);
    int p0 = b, p1 = b, p2 = b, p3 = b;
    int base = (2 * py) * 16 + 2 * px;
    for (int c = 0; c < 128; c++) {
        int sw = fsign(w2pw[o * 128 + c]);
        const signed char* d = db + c * 256 + base;
        p0 += sw * (int)d[0];
        p1 += sw * (int)d[1];
        p2 += sw * (int)d[16];
        p3 += sw * (int)d[17];
    }
    int s0 = (p0 > 0) - (p0 < 0), s1 = (p1 > 0) - (p1 < 0);
    int s2 = (p2 > 0) - (p2 < 0), s3 = (p3 > 0) - (p3 < 0);
    int mx = max(max(s0, s1), max(s2, s3));
    int k = o * 64 + py * 8 + px;
    hT2[(size_t)n * 16384 + k] = (signed char)mx;
}

// -------- Prep: decompose fc1_w [j][k] fp32 into 4 signed radix-128 int8 limbs on 2^-32 grid.
// BL[jm][k], jm = j*4 + m. Exact: w_q = d0 + 128 d1 + 2^14 d2 + 2^21 d3 = rint(w * 2^32).
__global__ void kprep(const float* __restrict__ fc1w, signed char* __restrict__ BL)
{
    int t = threadIdx.x;
    int b = blockIdx.x;              // 16384 blocks
    int j = b >> 4, kb = b & 15;
    int k0 = kb * 1024 + t * 4;
    float4 w = *(const float4*)(fc1w + (size_t)j * 16384 + k0);
    float we[4] = {w.x, w.y, w.z, w.w};
    int out[4] = {0, 0, 0, 0};
    #pragma unroll
    for (int e = 0; e < 4; e++) {
        int q = (int)rint((double)we[e] * 4294967296.0);
        q = min(max(q, -266338304), 266338304);   // |q| <= 127*2^21 (|w| <= 0.062, never hit)
        int d0 = ((q + 64) & 127) - 64; q = (q - d0) >> 7;
        int d1 = ((q + 64) & 127) - 64; q = (q - d1) >> 7;
        int d2 = ((q + 64) & 127) - 64; q = (q - d2) >> 7;
        int d3 = q;
        out[0] |= (d0 & 0xff) << (8 * e);
        out[1] |= (d1 & 0xff) << (8 * e);
        out[2] |= (d2 & 0xff) << (8 * e);
        out[3] |= (d3 & 0xff) << (8 * e);
    }
    #pragma unroll
    for (int m = 0; m < 4; m++)
        *(int*)(BL + (size_t)(j * 4 + m) * 16384 + k0) = out[m];
}

// -------- Kernel 4: fc1 GEMM via mfma_i32_16x16x64_i8, exact int32 accumulate.
// M=1024 (n, from hT2), N=4096 (jm, from BL), K=16384. Tiles 128x128x128.
// Epilogue: combine 4 limbs in fp64, add bias, sign -> hs [n][j] int8.
#define LDK 144   // 128 + 16 pad (bytes) per LDS row
__global__ __launch_bounds__(256) void k4_fc1_mfma(
    const signed char* __restrict__ hT2, const signed char* __restrict__ BL,
    const float* __restrict__ fc1b, signed char* __restrict__ hs)
{
    __shared__ __align__(16) char smem[65536];
    char* As = smem;                 // [128][LDK]
    char* Bs = smem + 128 * LDK;     // [128][LDK]
    int*  S  = (int*)smem;           // [128][128] epilogue overlay

    int t = threadIdx.x;
    int l = t & 63, wid = t >> 6;
    int nb0 = blockIdx.y * 128;      // n tile base
    int jb0 = blockIdx.x * 128;      // jm tile base
    int wn0 = (wid >> 1) * 64;       // wave sub-tile in n
    int wj0 = (wid & 1) * 64;        // wave sub-tile in jm

    v4i acc[4][4];
    #pragma unroll
    for (int i = 0; i < 4; i++)
        #pragma unroll
        for (int q = 0; q < 4; q++) acc[i][q] = (v4i){0, 0, 0, 0};

    int r   = t >> 1;                // staging row 0..127
    int seg = (t & 1) * 64;          // staging 64B segment

    int frow = l & 15;               // fragment row/col within 16
    int fk   = (l >> 4) * 16;        // fragment k byte offset

    for (int kt = 0; kt < 16384; kt += 128) {
        __syncthreads();
        {
            const int4* ga = (const int4*)(hT2 + (size_t)(nb0 + r) * 16384 + kt + seg);
            const int4* gb = (const int4*)(BL  + (size_t)(jb0 + r) * 16384 + kt + seg);
            int4 a0 = ga[0], a1 = ga[1], a2 = ga[2], a3 = ga[3];
            int4 b0 = gb[0], b1 = gb[1], b2 = gb[2], b3 = gb[3];
            int4* la = (int4*)&As[r * LDK + seg];
            int4* lb = (int4*)&Bs[r * LDK + seg];
            la[0] = a0; la[1] = a1; la[2] = a2; la[3] = a3;
            lb[0] = b0; lb[1] = b1; lb[2] = b2; lb[3] = b3;
        }
        __syncthreads();

        #pragma unroll
        for (int ks = 0; ks < 2; ks++) {
            v4i af[4], bf[4];
            #pragma unroll
            for (int i = 0; i < 4; i++)
                af[i] = *(const v4i*)&As[(wn0 + i * 16 + frow) * LDK + ks * 64 + fk];
            #pragma unroll
            for (int q = 0; q < 4; q++)
                bf[q] = *(const v4i*)&Bs[(wj0 + q * 16 + frow) * LDK + ks * 64 + fk];
            #pragma unroll
            for (int i = 0; i < 4; i++)
                #pragma unroll
                for (int q = 0; q < 4; q++)
                    acc[i][q] = __builtin_amdgcn_mfma_i32_16x16x64_i8(af[i], bf[q], acc[i][q], 0, 0, 0);
        }
    }

    __syncthreads();
    // write accumulators to S[n_local][jm_local] (C/D: col=lane&15, row=(lane>>4)*4+reg)
    #pragma unroll
    for (int i = 0; i < 4; i++)
        #pragma unroll
        for (int q = 0; q < 4; q++)
            #pragma unroll
            for (int rr = 0; rr < 4; rr++) {
                int n_l  = wn0 + i * 16 + (l >> 4) * 4 + rr;
                int jm_l = wj0 + q * 16 + (l & 15);
                S[n_l * 128 + jm_l] = acc[i][q][rr];
            }
    __syncthreads();

    // combine limbs: preact = 2^-32 * (S0 + 128 S1 + 2^14 S2 + 2^21 S3) + b
    const double SCALE = 1.0 / 4294967296.0;
    #pragma unroll
    for (int i = 0; i < 16; i++) {
        int idx = t * 16 + i;                 // 4096 outputs
        int n_l = idx >> 5, j_l = idx & 31;
        int4 s = *(const int4*)&S[n_l * 128 + j_l * 4];
        double val = (double)s.x + 128.0 * (double)s.y
                   + 16384.0 * (double)s.z + 2097152.0 * (double)s.w;
        int j = blockIdx.x * 32 + j_l;
        double p = val * SCALE + (double)fc1b[j];
        hs[(size_t)(nb0 + n_l) * 1024 + j] = (signed char)((p > 0.0) - (p < 0.0));
    }
}

// -------- Kernel 5: fc2 (1024x1024 -> 10), fp64 accumulate, fp32 out [1024,10]
__global__ void k5_fc2(const signed char* __restrict__ hs,
                       const float* __restrict__ fc2w, const float* __restrict__ fc2b,
                       float* __restrict__ out)
{
    int n = blockIdx.x * 256 + threadIdx.x;
    if (n >= 1024) return;
    double acc[10];
    #pragma unroll
    for (int m = 0; m < 10; m++) acc[m] = (double)fc2b[m];
    const signed char* hr = hs + (size_t)n * 1024;
    for (int j = 0; j < 1024; j++) {
        double dh = (double)(int)hr[j];
        #pragma unroll
        for (int m = 0; m < 10; m++) acc[m] += dh * (double)fc2w[m * 1024 + j];
    }
    #pragma unroll
    for (int m = 0; m < 10; m++) out[n * 10 + m] = (float)acc[m];
}

extern "C" void kernel_launch(void* const* d_in, const int* in_sizes, int n_in,
                              void* d_out, int out_size, void* d_ws, size_t ws_size,
                              hipStream_t stream)
{
    const float* x    = (const float*)d_in[0];
    const float* w1dw = (const float*)d_in[1];
    const float* b1dw = (const float*)d_in[2];
    const float* w1pw = (const float*)d_in[3];
    const float* b1pw = (const float*)d_in[4];
    const float* w2dw = (const float*)d_in[5];
    const float* b2dw = (const float*)d_in[6];
    const float* w2pw = (const float*)d_in[7];
    const float* b2pw = (const float*)d_in[8];
    const float* fc1w = (const float*)d_in[9];
    const float* fc1b = (const float*)d_in[10];
    const float* fc2w = (const float*)d_in[11];
    const float* fc2b = (const float*)d_in[12];
    float* out = (float*)d_out;

    // workspace layout (84,934,656 B total):
    //   phase A: pooled1 @0 (33.5MB), dw2 @33.5MB (33.5MB)
    //   phase B (after k3): BL @0 (64MiB) overwrites pooled1+dw2
    //   hT2 @64MiB (16MiB), hs @80MiB (1MiB)
    char* ws = (char*)d_ws;
    signed char* pooled1 = (signed char*)(ws);
    signed char* dw2     = (signed char*)(ws + 33554432);
    signed char* BL      = (signed char*)(ws);
    signed char* hT2     = (signed char*)(ws + 67108864);
    signed char* hs      = (signed char*)(ws + 83886080);

    hipLaunchKernelGGL(k1_conv1, dim3(1024),   dim3(256), 0, stream,
                       x, w1dw, b1dw, w1pw, b1pw, pooled1);
    hipLaunchKernelGGL(k2_dw2,   dim3(131072), dim3(256), 0, stream,
                       pooled1, w2dw, b2dw, dw2);
    hipLaunchKernelGGL(k3_pw2,   dim3(65536),  dim3(256), 0, stream,
                       dw2, w2pw, b2pw, hT2);
    hipLaunchKernelGGL(kprep,    dim3(16384),  dim3(256), 0, stream,
                       fc1w, BL);
    hipLaunchKernelGGL(k4_fc1_mfma, dim3(32, 8), dim3(256), 0, stream,
                       hT2, BL, fc1b, hs);
    hipLaunchKernelGGL(k5_fc2,   dim3(4),      dim3(256), 0, stream,
                       hs, fc2w, fc2b, out);
}

// Round 3
// 506.868 us; speedup vs baseline: 5.6629x; 2.8217x over previous
//
#include <hip/hip_runtime.h>

// BinaryConnectNet forward.
// R3: conv2-pw as per-sample int8 MFMA GEMM (maxpool folded onto the 4 C/D regs
// of each lane); c-innermost layouts end-to-end; k5 parallelized.

__device__ __forceinline__ int fsign(float v)  { return (v > 0.f) - (v < 0.f); }
__device__ __forceinline__ int dsign(double v) { return (v > 0.0) - (v < 0.0); }

typedef int v4i __attribute__((ext_vector_type(4)));

// -------- Kernel 1: conv1 dw(3x3,g=3) + pw(1x1 3->128) + sign + maxpool2
// -> pooled1T [n][y16][x16][c128] int8 (c contiguous).
__global__ void k1_conv1(const float* __restrict__ x,
                         const float* __restrict__ w1dw, const float* __restrict__ b1dw,
                         const float* __restrict__ w1pw, const float* __restrict__ b1pw,
                         signed char* __restrict__ pooled1T)
{
    __shared__ float sdw[27], sbdw[3], spw[384], sbpw[128];
    int t = threadIdx.x;
    if (t < 27) sdw[t] = (float)fsign(w1dw[t]);
    if (t < 3)  sbdw[t] = (float)fsign(b1dw[t]);
    for (int i = t; i < 384; i += 256) spw[i] = (float)fsign(w1pw[i]);
    if (t < 128) sbpw[t] = (float)fsign(b1pw[t]);
    __syncthreads();

    int g  = blockIdx.x * 256 + t;
    int px = g & 15, py = (g >> 4) & 15, n = g >> 8;   // pooled1 spatial coords [0,16)

    double h[3][4];
    const float* xb = x + (size_t)n * 3 * 1024;
    #pragma unroll
    for (int c = 0; c < 3; c++) {
        const float* xc = xb + c * 1024;
        #pragma unroll
        for (int dy = 0; dy < 2; dy++)
        #pragma unroll
        for (int dx = 0; dx < 2; dx++) {
            int y = 2 * py + dy, xx = 2 * px + dx;
            double acc = (double)sbdw[c];
            #pragma unroll
            for (int ky = 0; ky < 3; ky++) {
                int yy = y + ky - 1;
                if (yy < 0 || yy > 31) continue;
                #pragma unroll
                for (int kx = 0; kx < 3; kx++) {
                    int xxx = xx + kx - 1;
                    if (xxx < 0 || xxx > 31) continue;
                    acc += (double)sdw[c * 9 + ky * 3 + kx] * (double)xc[yy * 32 + xxx];
                }
            }
            h[c][dy * 2 + dx] = acc;
        }
    }

    signed char* outb = pooled1T + (size_t)n * 32768 + (py * 16 + px) * 128;
    int cur = 0;
    for (int o = 0; o < 128; o++) {
        double s0 = (double)spw[o * 3 + 0];
        double s1 = (double)spw[o * 3 + 1];
        double s2 = (double)spw[o * 3 + 2];
        double sb = (double)sbpw[o];
        int mx = -2;
        #pragma unroll
        for (int q = 0; q < 4; q++) {
            double p = s0 * h[0][q] + s1 * h[1][q] + s2 * h[2][q] + sb;
            int s = dsign(p);
            mx = s > mx ? s : mx;
        }
        cur |= (mx & 0xff) << ((o & 3) * 8);
        if ((o & 3) == 3) { *(int*)(outb + (o & ~3)) = cur; cur = 0; }
    }
}

// -------- Kernel 2: conv2 dw(3x3, g=128) -> dw2T [n][pos'][c] int8,
// pos' = (py*8+px)*4 + dy*2+dx  (pooled cell major, sub-position minor).
__global__ void k2_dw2(const signed char* __restrict__ pooled1T,
                       const float* __restrict__ w2dw, const float* __restrict__ b2dw,
                       signed char* __restrict__ dw2T)
{
    __shared__ signed char swt[1152];   // [tap][c]
    __shared__ signed char sbt[128];
    int t = threadIdx.x;
    for (int i = t; i < 1152; i += 256) {
        int c = i & 127, tap = i >> 7;
        swt[i] = (signed char)fsign(w2dw[c * 9 + tap]);
    }
    if (t < 128) sbt[t] = (signed char)fsign(b2dw[t]);
    __syncthreads();

    int b = blockIdx.x;               // 32768
    int n = b >> 5, pg = b & 31;
    int pos = pg * 8 + (t >> 5);      // raw 16x16 position
    int cg = t & 31;                  // 4-channel group
    int y = pos >> 4, x = pos & 15;

    int acc0 = (int)sbt[cg * 4 + 0];
    int acc1 = (int)sbt[cg * 4 + 1];
    int acc2 = (int)sbt[cg * 4 + 2];
    int acc3 = (int)sbt[cg * 4 + 3];

    const signed char* pb = pooled1T + (size_t)n * 32768;
    #pragma unroll
    for (int ky = 0; ky < 3; ky++) {
        int yy = y + ky - 1;
        if (yy < 0 || yy > 15) continue;
        #pragma unroll
        for (int kx = 0; kx < 3; kx++) {
            int xxx = x + kx - 1;
            if (xxx < 0 || xxx > 15) continue;
            int v = *(const int*)(pb + (yy * 16 + xxx) * 128 + cg * 4);
            int w = *(const int*)(swt + (ky * 3 + kx) * 128 + cg * 4);
            acc0 += (int)(signed char)(v)       * (int)(signed char)(w);
            acc1 += (int)(signed char)(v >> 8)  * (int)(signed char)(w >> 8);
            acc2 += (int)(signed char)(v >> 16) * (int)(signed char)(w >> 16);
            acc3 += (int)(signed char)(v >> 24) * (int)(signed char)(w >> 24);
        }
    }
    int outv = (acc0 & 0xff) | ((acc1 & 0xff) << 8) | ((acc2 & 0xff) << 16) | ((acc3 & 0xff) << 24);
    int py = y >> 1, dy = y & 1, px2 = x >> 1, dx = x & 1;
    int posp = (py * 8 + px2) * 4 + dy * 2 + dx;
    *(int*)(dw2T + (size_t)n * 32768 + posp * 128 + cg * 4) = outv;
}

// -------- Prep: sign tables for conv2-pw B matrix.
__global__ void kprep2(const float* __restrict__ w2pw, const float* __restrict__ b2pw,
                       signed char* __restrict__ w2s, signed char* __restrict__ b2s)
{
    int idx = blockIdx.x * 256 + threadIdx.x;   // 8192
    float4 w = *(const float4*)(w2pw + (size_t)idx * 4);
    int o = (fsign(w.x) & 0xff) | ((fsign(w.y) & 0xff) << 8)
          | ((fsign(w.z) & 0xff) << 16) | ((fsign(w.w) & 0xff) << 24);
    *(int*)(w2s + (size_t)idx * 4) = o;
    if (idx < 64) {
        float4 bb = ((const float4*)b2pw)[idx];
        int ob = (fsign(bb.x) & 0xff) | ((fsign(bb.y) & 0xff) << 8)
               | ((fsign(bb.z) & 0xff) << 16) | ((fsign(bb.w) & 0xff) << 24);
        *(int*)(b2s + (size_t)idx * 4) = ob;
    }
}

// -------- Kernel 3: conv2 pw as per-sample MFMA GEMM + sign + maxpool -> hT2 [n][16384]
// A = dw2T[n] (256 pos' x 128 c), B = w2s (256 o x 128 c), exact i32.
// C/D: row=pos' (4 regs = 4 sub-positions of one pooled cell), col=o.
__global__ __launch_bounds__(256) void k3_pw2_mfma(
    const signed char* __restrict__ dw2T, const signed char* __restrict__ w2s,
    const signed char* __restrict__ b2s, signed char* __restrict__ hT2)
{
    __shared__ __align__(16) signed char As[256 * 144];   // 36864
    __shared__ __align__(16) signed char Bs[64 * 144];    //  9216
    __shared__ __align__(16) signed char Os[4096];
    int t = threadIdx.x, l = t & 63, wid = t >> 6;
    int n = blockIdx.x;

    const signed char* an = dw2T + (size_t)n * 32768;
    #pragma unroll
    for (int i = 0; i < 8; i++) {
        int row = i * 32 + (t >> 3), seg = (t & 7) * 16;
        *(int4*)&As[row * 144 + seg] = *(const int4*)(an + row * 128 + seg);
    }
    __syncthreads();

    v4i af[4][2];
    #pragma unroll
    for (int i = 0; i < 4; i++)
        #pragma unroll
        for (int ks = 0; ks < 2; ks++)
            af[i][ks] = *(const v4i*)&As[((wid * 4 + i) * 16 + (l & 15)) * 144 + ks * 64 + (l >> 4) * 16];

    for (int oc = 0; oc < 4; oc++) {
        __syncthreads();   // Bs/Os reuse guard
        #pragma unroll
        for (int i = 0; i < 2; i++) {
            int row = i * 32 + (t >> 3), seg = (t & 7) * 16;
            *(int4*)&Bs[row * 144 + seg] = *(const int4*)(w2s + (size_t)(oc * 64 + row) * 128 + seg);
        }
        __syncthreads();

        v4i acc[4][4];
        #pragma unroll
        for (int i = 0; i < 4; i++)
            #pragma unroll
            for (int jt = 0; jt < 4; jt++) acc[i][jt] = (v4i){0, 0, 0, 0};

        #pragma unroll
        for (int ks = 0; ks < 2; ks++) {
            v4i bf[4];
            #pragma unroll
            for (int jt = 0; jt < 4; jt++)
                bf[jt] = *(const v4i*)&Bs[(jt * 16 + (l & 15)) * 144 + ks * 64 + (l >> 4) * 16];
            #pragma unroll
            for (int i = 0; i < 4; i++)
                #pragma unroll
                for (int jt = 0; jt < 4; jt++)
                    acc[i][jt] = __builtin_amdgcn_mfma_i32_16x16x64_i8(af[i][ks], bf[jt], acc[i][jt], 0, 0, 0);
        }

        #pragma unroll
        for (int jt = 0; jt < 4; jt++) {
            int o_l = jt * 16 + (l & 15);
            int bia = (int)b2s[oc * 64 + o_l];
            #pragma unroll
            for (int i = 0; i < 4; i++) {
                int mx = -2;
                #pragma unroll
                for (int rr = 0; rr < 4; rr++) {
                    int p = acc[i][jt][rr] + bia;
                    int s = (p > 0) - (p < 0);
                    mx = s > mx ? s : mx;
                }
                int pp = (wid * 4 + i) * 4 + (l >> 4);
                Os[o_l * 64 + pp] = (signed char)mx;
            }
        }
        __syncthreads();
        *(int4*)&hT2[(size_t)n * 16384 + oc * 4096 + t * 16] = *(const int4*)&Os[t * 16];
    }
}

// -------- Prep: fc1_w -> 4 signed radix-128 int8 limbs on 2^-32 grid (exact).
__global__ void kprep(const float* __restrict__ fc1w, signed char* __restrict__ BL)
{
    int t = threadIdx.x;
    int b = blockIdx.x;              // 16384
    int j = b >> 4, kb = b & 15;
    int k0 = kb * 1024 + t * 4;
    float4 w = *(const float4*)(fc1w + (size_t)j * 16384 + k0);
    float we[4] = {w.x, w.y, w.z, w.w};
    int out[4] = {0, 0, 0, 0};
    #pragma unroll
    for (int e = 0; e < 4; e++) {
        int q = (int)rint((double)we[e] * 4294967296.0);
        q = min(max(q, -266338304), 266338304);
        int d0 = ((q + 64) & 127) - 64; q = (q - d0) >> 7;
        int d1 = ((q + 64) & 127) - 64; q = (q - d1) >> 7;
        int d2 = ((q + 64) & 127) - 64; q = (q - d2) >> 7;
        int d3 = q;
        out[0] |= (d0 & 0xff) << (8 * e);
        out[1] |= (d1 & 0xff) << (8 * e);
        out[2] |= (d2 & 0xff) << (8 * e);
        out[3] |= (d3 & 0xff) << (8 * e);
    }
    #pragma unroll
    for (int m = 0; m < 4; m++)
        *(int*)(BL + (size_t)(j * 4 + m) * 16384 + k0) = out[m];
}

// -------- Kernel 4: fc1 GEMM via mfma_i32_16x16x64_i8, exact int32, limb-combine fp64.
#define LDK 144
__global__ __launch_bounds__(256) void k4_fc1_mfma(
    const signed char* __restrict__ hT2, const signed char* __restrict__ BL,
    const float* __restrict__ fc1b, signed char* __restrict__ hs)
{
    __shared__ __align__(16) char smem[65536];
    char* As = smem;
    char* Bs = smem + 128 * LDK;
    int*  S  = (int*)smem;

    int t = threadIdx.x;
    int l = t & 63, wid = t >> 6;
    int nb0 = blockIdx.y * 128;
    int jb0 = blockIdx.x * 128;
    int wn0 = (wid >> 1) * 64;
    int wj0 = (wid & 1) * 64;

    v4i acc[4][4];
    #pragma unroll
    for (int i = 0; i < 4; i++)
        #pragma unroll
        for (int q = 0; q < 4; q++) acc[i][q] = (v4i){0, 0, 0, 0};

    int r   = t >> 1;
    int seg = (t & 1) * 64;
    int frow = l & 15;
    int fk   = (l >> 4) * 16;

    for (int kt = 0; kt < 16384; kt += 128) {
        __syncthreads();
        {
            const int4* ga = (const int4*)(hT2 + (size_t)(nb0 + r) * 16384 + kt + seg);
            const int4* gb = (const int4*)(BL  + (size_t)(jb0 + r) * 16384 + kt + seg);
            int4 a0 = ga[0], a1 = ga[1], a2 = ga[2], a3 = ga[3];
            int4 b0 = gb[0], b1 = gb[1], b2 = gb[2], b3 = gb[3];
            int4* la = (int4*)&As[r * LDK + seg];
            int4* lb = (int4*)&Bs[r * LDK + seg];
            la[0] = a0; la[1] = a1; la[2] = a2; la[3] = a3;
            lb[0] = b0; lb[1] = b1; lb[2] = b2; lb[3] = b3;
        }
        __syncthreads();

        #pragma unroll
        for (int ks = 0; ks < 2; ks++) {
            v4i af[4], bf[4];
            #pragma unroll
            for (int i = 0; i < 4; i++)
                af[i] = *(const v4i*)&As[(wn0 + i * 16 + frow) * LDK + ks * 64 + fk];
            #pragma unroll
            for (int q = 0; q < 4; q++)
                bf[q] = *(const v4i*)&Bs[(wj0 + q * 16 + frow) * LDK + ks * 64 + fk];
            #pragma unroll
            for (int i = 0; i < 4; i++)
                #pragma unroll
                for (int q = 0; q < 4; q++)
                    acc[i][q] = __builtin_amdgcn_mfma_i32_16x16x64_i8(af[i], bf[q], acc[i][q], 0, 0, 0);
        }
    }

    __syncthreads();
    #pragma unroll
    for (int i = 0; i < 4; i++)
        #pragma unroll
        for (int q = 0; q < 4; q++)
            #pragma unroll
            for (int rr = 0; rr < 4; rr++) {
                int n_l  = wn0 + i * 16 + (l >> 4) * 4 + rr;
                int jm_l = wj0 + q * 16 + (l & 15);
                S[n_l * 128 + jm_l] = acc[i][q][rr];
            }
    __syncthreads();

    const double SCALE = 1.0 / 4294967296.0;
    #pragma unroll
    for (int i = 0; i < 16; i++) {
        int idx = t * 16 + i;
        int n_l = idx >> 5, j_l = idx & 31;
        int4 s = *(const int4*)&S[n_l * 128 + j_l * 4];
        double val = (double)s.x + 128.0 * (double)s.y
                   + 16384.0 * (double)s.z + 2097152.0 * (double)s.w;
        int j = blockIdx.x * 32 + j_l;
        double p = val * SCALE + (double)fc1b[j];
        hs[(size_t)(nb0 + n_l) * 1024 + j] = (signed char)((p > 0.0) - (p < 0.0));
    }
}

// -------- Kernel 5: fc2, thread per (n,m) output, fp64 accumulate.
__global__ void k5_fc2(const signed char* __restrict__ hs,
                       const float* __restrict__ fc2w, const float* __restrict__ fc2b,
                       float* __restrict__ out)
{
    int idx = blockIdx.x * 256 + threadIdx.x;
    if (idx >= 10240) return;
    int n = idx / 10, m = idx - n * 10;
    const signed char* hr = hs + (size_t)n * 1024;
    const float* wr = fc2w + (size_t)m * 1024;
    double acc = (double)fc2b[m];
    for (int jb = 0; jb < 1024; jb += 16) {
        int4 hv = *(const int4*)(hr + jb);
        int wd[4] = {hv.x, hv.y, hv.z, hv.w};
        #pragma unroll
        for (int u = 0; u < 4; u++)
            #pragma unroll
            for (int e = 0; e < 4; e++)
                acc += (double)(signed char)(wd[u] >> (8 * e)) * (double)wr[jb + u * 4 + e];
    }
    out[idx] = (float)acc;
}

extern "C" void kernel_launch(void* const* d_in, const int* in_sizes, int n_in,
                              void* d_out, int out_size, void* d_ws, size_t ws_size,
                              hipStream_t stream)
{
    const float* x    = (const float*)d_in[0];
    const float* w1dw = (const float*)d_in[1];
    const float* b1dw = (const float*)d_in[2];
    const float* w1pw = (const float*)d_in[3];
    const float* b1pw = (const float*)d_in[4];
    const float* w2dw = (const float*)d_in[5];
    const float* b2dw = (const float*)d_in[6];
    const float* w2pw = (const float*)d_in[7];
    const float* b2pw = (const float*)d_in[8];
    const float* fc1w = (const float*)d_in[9];
    const float* fc1b = (const float*)d_in[10];
    const float* fc2w = (const float*)d_in[11];
    const float* fc2b = (const float*)d_in[12];
    float* out = (float*)d_out;

    // workspace (<= 84,934,656 B, as in passing rounds):
    //   pooled1T @0        33.5MB   (dead after k2)
    //   dw2T     @33.5MB   33.5MB   (dead after k3)
    //   hT2      @64MiB    16MiB    (dead after k4)
    //   w2s/b2s  @80MiB    33KB     (dead after k3; region reused as hs)
    //   BL       @0        64MiB    (written after k3, dead after k4)
    //   hs       @80MiB    1MiB
    char* ws = (char*)d_ws;
    signed char* pooled1T = (signed char*)(ws);
    signed char* dw2T     = (signed char*)(ws + 33554432);
    signed char* hT2      = (signed char*)(ws + 67108864);
    signed char* w2s      = (signed char*)(ws + 83886080);
    signed char* b2s      = (signed char*)(ws + 83886080 + 32768);
    signed char* BL       = (signed char*)(ws);
    signed char* hs       = (signed char*)(ws + 83886080);

    hipLaunchKernelGGL(k1_conv1,    dim3(1024),  dim3(256), 0, stream,
                       x, w1dw, b1dw, w1pw, b1pw, pooled1T);
    hipLaunchKernelGGL(k2_dw2,      dim3(32768), dim3(256), 0, stream,
                       pooled1T, w2dw, b2dw, dw2T);
    hipLaunchKernelGGL(kprep2,      dim3(32),    dim3(256), 0, stream,
                       w2pw, b2pw, w2s, b2s);
    hipLaunchKernelGGL(k3_pw2_mfma, dim3(1024),  dim3(256), 0, stream,
                       dw2T, w2s, b2s, hT2);
    hipLaunchKernelGGL(kprep,       dim3(16384), dim3(256), 0, stream,
                       fc1w, BL);
    hipLaunchKernelGGL(k4_fc1_mfma, dim3(32, 8), dim3(256), 0, stream,
                       hT2, BL, fc1b, hs);
    hipLaunchKernelGGL(k5_fc2,      dim3(40),    dim3(256), 0, stream,
                       hs, fc2w, fc2b, out);
}

// Round 4
// 471.491 us; speedup vs baseline: 6.0878x; 1.0750x over previous
//
#include <hip/hip_runtime.h>

// BinaryConnectNet forward.
// R4: k4 rebuilt — 512 threads/block, explicit LDS double-buffer with
// global_load_lds(16B) async staging, one barrier per K-iter. k2 XOR trick.

__device__ __forceinline__ int fsign(float v)  { return (v > 0.f) - (v < 0.f); }
__device__ __forceinline__ int dsign(double v) { return (v > 0.0) - (v < 0.0); }

typedef int v4i __attribute__((ext_vector_type(4)));

__device__ __forceinline__ void async16(const signed char* g, signed char* l) {
    __builtin_amdgcn_global_load_lds(
        (const __attribute__((address_space(1))) void*)g,
        (__attribute__((address_space(3))) void*)l, 16, 0, 0);
}

// -------- Kernel 1: conv1 dw(3x3,g=3) + pw(1x1 3->128) + sign + maxpool2
// -> pooled1T [n][y16][x16][c128] int8 (c contiguous).
__global__ void k1_conv1(const float* __restrict__ x,
                         const float* __restrict__ w1dw, const float* __restrict__ b1dw,
                         const float* __restrict__ w1pw, const float* __restrict__ b1pw,
                         signed char* __restrict__ pooled1T)
{
    __shared__ float sdw[27], sbdw[3], spw[384], sbpw[128];
    int t = threadIdx.x;
    if (t < 27) sdw[t] = (float)fsign(w1dw[t]);
    if (t < 3)  sbdw[t] = (float)fsign(b1dw[t]);
    for (int i = t; i < 384; i += 256) spw[i] = (float)fsign(w1pw[i]);
    if (t < 128) sbpw[t] = (float)fsign(b1pw[t]);
    __syncthreads();

    int g  = blockIdx.x * 256 + t;
    int px = g & 15, py = (g >> 4) & 15, n = g >> 8;

    double h[3][4];
    const float* xb = x + (size_t)n * 3 * 1024;
    #pragma unroll
    for (int c = 0; c < 3; c++) {
        const float* xc = xb + c * 1024;
        #pragma unroll
        for (int dy = 0; dy < 2; dy++)
        #pragma unroll
        for (int dx = 0; dx < 2; dx++) {
            int y = 2 * py + dy, xx = 2 * px + dx;
            double acc = (double)sbdw[c];
            #pragma unroll
            for (int ky = 0; ky < 3; ky++) {
                int yy = y + ky - 1;
                if (yy < 0 || yy > 31) continue;
                #pragma unroll
                for (int kx = 0; kx < 3; kx++) {
                    int xxx = xx + kx - 1;
                    if (xxx < 0 || xxx > 31) continue;
                    acc += (double)sdw[c * 9 + ky * 3 + kx] * (double)xc[yy * 32 + xxx];
                }
            }
            h[c][dy * 2 + dx] = acc;
        }
    }

    signed char* outb = pooled1T + (size_t)n * 32768 + (py * 16 + px) * 128;
    int cur = 0;
    for (int o = 0; o < 128; o++) {
        double s0 = (double)spw[o * 3 + 0];
        double s1 = (double)spw[o * 3 + 1];
        double s2 = (double)spw[o * 3 + 2];
        double sb = (double)sbpw[o];
        int mx = -2;
        #pragma unroll
        for (int q = 0; q < 4; q++) {
            double p = s0 * h[0][q] + s1 * h[1][q] + s2 * h[2][q] + sb;
            int s = dsign(p);
            mx = s > mx ? s : mx;
        }
        cur |= (mx & 0xff) << ((o & 3) * 8);
        if ((o & 3) == 3) { *(int*)(outb + (o & ~3)) = cur; cur = 0; }
    }
}

// -------- Kernel 2: conv2 dw(3x3, g=128) -> dw2T [n][pos'][c] int8.
// pos' = (py*8+px)*4 + dy*2+dx. XOR trick: prod(+-1) via v^w bit-1 count.
__global__ void k2_dw2(const signed char* __restrict__ pooled1T,
                       const float* __restrict__ w2dw, const float* __restrict__ b2dw,
                       signed char* __restrict__ dw2T)
{
    __shared__ int swt[288];    // bytes [tap][c] = sign as 0x01/0xff
    __shared__ int sbt[32];
    int t = threadIdx.x;
    for (int i = t; i < 1152; i += 256) {
        int c = i & 127, tap = i >> 7;
        ((signed char*)swt)[tap * 128 + c] = (signed char)fsign(w2dw[c * 9 + tap]);
    }
    if (t < 128) ((signed char*)sbt)[t] = (signed char)fsign(b2dw[t]);
    __syncthreads();

    int b = blockIdx.x;               // 32768
    int n = b >> 5, pg = b & 31;
    int pos = pg * 8 + (t >> 5);
    int cg = t & 31;
    int y = pos >> 4, x = pos & 15;

    int wv[9];
    #pragma unroll
    for (int tap = 0; tap < 9; tap++) wv[tap] = swt[tap * 32 + cg];

    int cnt = 0;
    const signed char* pb = pooled1T + (size_t)n * 32768;
    #pragma unroll
    for (int ky = 0; ky < 3; ky++) {
        int yy = y + ky - 1;
        if (yy < 0 || yy > 15) continue;
        #pragma unroll
        for (int kx = 0; kx < 3; kx++) {
            int xxx = x + kx - 1;
            if (xxx < 0 || xxx > 15) continue;
            int v = *(const int*)(pb + (yy * 16 + xxx) * 128 + cg * 4);
            int xr = v ^ wv[ky * 3 + kx];
            cnt += (xr >> 1) & 0x01010101;   // byte-wise: 1 if product == -1
        }
    }
    int valid = (1 + (y > 0) + (y < 15)) * (1 + (x > 0) + (x < 15));
    int sb = sbt[cg];
    int outv = 0;
    #pragma unroll
    for (int e = 0; e < 4; e++) {
        int cc = (cnt >> (8 * e)) & 0xff;
        int bb = (int)(signed char)((sb >> (8 * e)) & 0xff);
        int val = bb + valid - 2 * cc;
        outv |= (val & 0xff) << (8 * e);
    }
    int py = y >> 1, dy = y & 1, px2 = x >> 1, dx = x & 1;
    int posp = (py * 8 + px2) * 4 + dy * 2 + dx;
    *(int*)(dw2T + (size_t)n * 32768 + posp * 128 + cg * 4) = outv;
}

// -------- Prep: sign tables for conv2-pw B matrix.
__global__ void kprep2(const float* __restrict__ w2pw, const float* __restrict__ b2pw,
                       signed char* __restrict__ w2s, signed char* __restrict__ b2s)
{
    int idx = blockIdx.x * 256 + threadIdx.x;   // 8192
    float4 w = *(const float4*)(w2pw + (size_t)idx * 4);
    int o = (fsign(w.x) & 0xff) | ((fsign(w.y) & 0xff) << 8)
          | ((fsign(w.z) & 0xff) << 16) | ((fsign(w.w) & 0xff) << 24);
    *(int*)(w2s + (size_t)idx * 4) = o;
    if (idx < 64) {
        float4 bb = ((const float4*)b2pw)[idx];
        int ob = (fsign(bb.x) & 0xff) | ((fsign(bb.y) & 0xff) << 8)
               | ((fsign(bb.z) & 0xff) << 16) | ((fsign(bb.w) & 0xff) << 24);
        *(int*)(b2s + (size_t)idx * 4) = ob;
    }
}

// -------- Kernel 3: conv2 pw as per-sample MFMA GEMM + sign + maxpool -> hT2 [n][16384]
__global__ __launch_bounds__(256) void k3_pw2_mfma(
    const signed char* __restrict__ dw2T, const signed char* __restrict__ w2s,
    const signed char* __restrict__ b2s, signed char* __restrict__ hT2)
{
    __shared__ __align__(16) signed char As[256 * 144];
    __shared__ __align__(16) signed char Bs[64 * 144];
    __shared__ __align__(16) signed char Os[4096];
    int t = threadIdx.x, l = t & 63, wid = t >> 6;
    int n = blockIdx.x;

    const signed char* an = dw2T + (size_t)n * 32768;
    #pragma unroll
    for (int i = 0; i < 8; i++) {
        int row = i * 32 + (t >> 3), seg = (t & 7) * 16;
        *(int4*)&As[row * 144 + seg] = *(const int4*)(an + row * 128 + seg);
    }
    __syncthreads();

    v4i af[4][2];
    #pragma unroll
    for (int i = 0; i < 4; i++)
        #pragma unroll
        for (int ks = 0; ks < 2; ks++)
            af[i][ks] = *(const v4i*)&As[((wid * 4 + i) * 16 + (l & 15)) * 144 + ks * 64 + (l >> 4) * 16];

    for (int oc = 0; oc < 4; oc++) {
        __syncthreads();
        #pragma unroll
        for (int i = 0; i < 2; i++) {
            int row = i * 32 + (t >> 3), seg = (t & 7) * 16;
            *(int4*)&Bs[row * 144 + seg] = *(const int4*)(w2s + (size_t)(oc * 64 + row) * 128 + seg);
        }
        __syncthreads();

        v4i acc[4][4];
        #pragma unroll
        for (int i = 0; i < 4; i++)
            #pragma unroll
            for (int jt = 0; jt < 4; jt++) acc[i][jt] = (v4i){0, 0, 0, 0};

        #pragma unroll
        for (int ks = 0; ks < 2; ks++) {
            v4i bf[4];
            #pragma unroll
            for (int jt = 0; jt < 4; jt++)
                bf[jt] = *(const v4i*)&Bs[(jt * 16 + (l & 15)) * 144 + ks * 64 + (l >> 4) * 16];
            #pragma unroll
            for (int i = 0; i < 4; i++)
                #pragma unroll
                for (int jt = 0; jt < 4; jt++)
                    acc[i][jt] = __builtin_amdgcn_mfma_i32_16x16x64_i8(af[i][ks], bf[jt], acc[i][jt], 0, 0, 0);
        }

        #pragma unroll
        for (int jt = 0; jt < 4; jt++) {
            int o_l = jt * 16 + (l & 15);
            int bia = (int)b2s[oc * 64 + o_l];
            #pragma unroll
            for (int i = 0; i < 4; i++) {
                int mx = -2;
                #pragma unroll
                for (int rr = 0; rr < 4; rr++) {
                    int p = acc[i][jt][rr] + bia;
                    int s = (p > 0) - (p < 0);
                    mx = s > mx ? s : mx;
                }
                int pp = (wid * 4 + i) * 4 + (l >> 4);
                Os[o_l * 64 + pp] = (signed char)mx;
            }
        }
        __syncthreads();
        *(int4*)&hT2[(size_t)n * 16384 + oc * 4096 + t * 16] = *(const int4*)&Os[t * 16];
    }
}

// -------- Prep: fc1_w -> 4 signed radix-128 int8 limbs on 2^-32 grid (exact).
__global__ void kprep(const float* __restrict__ fc1w, signed char* __restrict__ BL)
{
    int t = threadIdx.x;
    int b = blockIdx.x;              // 16384
    int j = b >> 4, kb = b & 15;
    int k0 = kb * 1024 + t * 4;
    float4 w = *(const float4*)(fc1w + (size_t)j * 16384 + k0);
    float we[4] = {w.x, w.y, w.z, w.w};
    int out[4] = {0, 0, 0, 0};
    #pragma unroll
    for (int e = 0; e < 4; e++) {
        int q = (int)rint((double)we[e] * 4294967296.0);
        q = min(max(q, -266338304), 266338304);
        int d0 = ((q + 64) & 127) - 64; q = (q - d0) >> 7;
        int d1 = ((q + 64) & 127) - 64; q = (q - d1) >> 7;
        int d2 = ((q + 64) & 127) - 64; q = (q - d2) >> 7;
        int d3 = q;
        out[0] |= (d0 & 0xff) << (8 * e);
        out[1] |= (d1 & 0xff) << (8 * e);
        out[2] |= (d2 & 0xff) << (8 * e);
        out[3] |= (d3 & 0xff) << (8 * e);
    }
    #pragma unroll
    for (int m = 0; m < 4; m++)
        *(int*)(BL + (size_t)(j * 4 + m) * 16384 + k0) = out[m];
}

// -------- Kernel 4: fc1 GEMM, 512 thr, double-buffered global_load_lds staging.
// M=1024(n) x N=4096(jm) x K=16384, tiles 128x128x128. Exact i32; fp64 combine.
__global__ __launch_bounds__(512) void k4_fc1_mfma(
    const signed char* __restrict__ hT2, const signed char* __restrict__ BL,
    const float* __restrict__ fc1b, signed char* __restrict__ hs)
{
    __shared__ __align__(16) signed char smem[65536];   // 2 x (A 16K + B 16K); S overlay
    int t = threadIdx.x, l = t & 63, wid = t >> 6;
    int nb0 = blockIdx.y * 128, jb0 = blockIdx.x * 128;
    int wn0 = (wid >> 1) * 32;    // wave n-subtile (32 rows)
    int wj0 = (wid & 1) * 64;     // wave jm-subtile (64 rows)

    int srow = l >> 3, sseg = (l & 7) * 16;   // staging lane mapping (8 rows x 8 segs)
    const signed char* gA = hT2 + (size_t)(nb0 + wid * 16 + srow) * 16384 + sseg;
    const signed char* gB = BL  + (size_t)(jb0 + wid * 16 + srow) * 16384 + sseg;

    v4i acc[2][4];
    #pragma unroll
    for (int i = 0; i < 2; i++)
        #pragma unroll
        for (int q = 0; q < 4; q++) acc[i][q] = (v4i){0, 0, 0, 0};

    // stage buf 0, kt = 0
    {
        signed char* As = smem;
        signed char* Bs = smem + 16384;
        #pragma unroll
        for (int i = 0; i < 2; i++) {
            async16(gA + (size_t)i * 8 * 16384, As + (wid * 16 + i * 8) * 128);
            async16(gB + (size_t)i * 8 * 16384, Bs + (wid * 16 + i * 8) * 128);
        }
    }

    for (int it = 0; it < 128; it++) {
        __syncthreads();   // drains vmcnt: staged buf (it&1) complete; prev compute done
        if (it + 1 < 128) {
            int kt = (it + 1) * 128;
            signed char* As = smem + ((it + 1) & 1) * 32768;
            signed char* Bs = As + 16384;
            #pragma unroll
            for (int i = 0; i < 2; i++) {
                async16(gA + (size_t)i * 8 * 16384 + kt, As + (wid * 16 + i * 8) * 128);
                async16(gB + (size_t)i * 8 * 16384 + kt, Bs + (wid * 16 + i * 8) * 128);
            }
        }
        const signed char* As = smem + (it & 1) * 32768;
        const signed char* Bs = As + 16384;
        #pragma unroll
        for (int ks = 0; ks < 2; ks++) {
            v4i af[2], bf[4];
            #pragma unroll
            for (int i = 0; i < 2; i++)
                af[i] = *(const v4i*)&As[(wn0 + i * 16 + (l & 15)) * 128 + ks * 64 + (l >> 4) * 16];
            #pragma unroll
            for (int q = 0; q < 4; q++)
                bf[q] = *(const v4i*)&Bs[(wj0 + q * 16 + (l & 15)) * 128 + ks * 64 + (l >> 4) * 16];
            #pragma unroll
            for (int i = 0; i < 2; i++)
                #pragma unroll
                for (int q = 0; q < 4; q++)
                    acc[i][q] = __builtin_amdgcn_mfma_i32_16x16x64_i8(af[i], bf[q], acc[i][q], 0, 0, 0);
        }
    }

    __syncthreads();
    int* S = (int*)smem;    // [128 n][128 jm]
    #pragma unroll
    for (int i = 0; i < 2; i++)
        #pragma unroll
        for (int q = 0; q < 4; q++)
            #pragma unroll
            for (int rr = 0; rr < 4; rr++) {
                int n_l  = wn0 + i * 16 + (l >> 4) * 4 + rr;
                int jm_l = wj0 + q * 16 + (l & 15);
                S[n_l * 128 + jm_l] = acc[i][q][rr];
            }
    __syncthreads();

    const double SCALE = 1.0 / 4294967296.0;
    #pragma unroll
    for (int i = 0; i < 8; i++) {
        int idx = t * 8 + i;                  // 4096 outputs: 128 n x 32 j
        int n_l = idx >> 5, j_l = idx & 31;
        int4 s = *(const int4*)&S[n_l * 128 + j_l * 4];
        double val = (double)s.x + 128.0 * (double)s.y
                   + 16384.0 * (double)s.z + 2097152.0 * (double)s.w;
        int j = blockIdx.x * 32 + j_l;
        double p = val * SCALE + (double)fc1b[j];
        hs[(size_t)(nb0 + n_l) * 1024 + j] = (signed char)((p > 0.0) - (p < 0.0));
    }
}

// -------- Kernel 5: fc2, thread per (n,m) output, fp64 accumulate.
__global__ void k5_fc2(const signed char* __restrict__ hs,
                       const float* __restrict__ fc2w, const float* __restrict__ fc2b,
                       float* __restrict__ out)
{
    int idx = blockIdx.x * 256 + threadIdx.x;
    if (idx >= 10240) return;
    int n = idx / 10, m = idx - n * 10;
    const signed char* hr = hs + (size_t)n * 1024;
    const float* wr = fc2w + (size_t)m * 1024;
    double acc = (double)fc2b[m];
    for (int jb = 0; jb < 1024; jb += 16) {
        int4 hv = *(const int4*)(hr + jb);
        int wd[4] = {hv.x, hv.y, hv.z, hv.w};
        #pragma unroll
        for (int u = 0; u < 4; u++)
            #pragma unroll
            for (int e = 0; e < 4; e++)
                acc += (double)(signed char)(wd[u] >> (8 * e)) * (double)wr[jb + u * 4 + e];
    }
    out[idx] = (float)acc;
}

extern "C" void kernel_launch(void* const* d_in, const int* in_sizes, int n_in,
                              void* d_out, int out_size, void* d_ws, size_t ws_size,
                              hipStream_t stream)
{
    const float* x    = (const float*)d_in[0];
    const float* w1dw = (const float*)d_in[1];
    const float* b1dw = (const float*)d_in[2];
    const float* w1pw = (const float*)d_in[3];
    const float* b1pw = (const float*)d_in[4];
    const float* w2dw = (const float*)d_in[5];
    const float* b2dw = (const float*)d_in[6];
    const float* w2pw = (const float*)d_in[7];
    const float* b2pw = (const float*)d_in[8];
    const float* fc1w = (const float*)d_in[9];
    const float* fc1b = (const float*)d_in[10];
    const float* fc2w = (const float*)d_in[11];
    const float* fc2b = (const float*)d_in[12];
    float* out = (float*)d_out;

    char* ws = (char*)d_ws;
    signed char* pooled1T = (signed char*)(ws);
    signed char* dw2T     = (signed char*)(ws + 33554432);
    signed char* hT2      = (signed char*)(ws + 67108864);
    signed char* w2s      = (signed char*)(ws + 83886080);
    signed char* b2s      = (signed char*)(ws + 83886080 + 32768);
    signed char* BL       = (signed char*)(ws);
    signed char* hs       = (signed char*)(ws + 83886080);

    hipLaunchKernelGGL(k1_conv1,    dim3(1024),  dim3(256), 0, stream,
                       x, w1dw, b1dw, w1pw, b1pw, pooled1T);
    hipLaunchKernelGGL(k2_dw2,      dim3(32768), dim3(256), 0, stream,
                       pooled1T, w2dw, b2dw, dw2T);
    hipLaunchKernelGGL(kprep2,      dim3(32),    dim3(256), 0, stream,
                       w2pw, b2pw, w2s, b2s);
    hipLaunchKernelGGL(k3_pw2_mfma, dim3(1024),  dim3(256), 0, stream,
                       dw2T, w2s, b2s, hT2);
    hipLaunchKernelGGL(kprep,       dim3(16384), dim3(256), 0, stream,
                       fc1w, BL);
    hipLaunchKernelGGL(k4_fc1_mfma, dim3(32, 8), dim3(512), 0, stream,
                       hT2, BL, fc1b, hs);
    hipLaunchKernelGGL(k5_fc2,      dim3(40),    dim3(256), 0, stream,
                       hs, fc2w, fc2b, out);
}

// Round 5
// 425.202 us; speedup vs baseline: 6.7506x; 1.1089x over previous
//
#include <hip/hip_runtime.h>

// BinaryConnectNet forward.
// R5: k4 XOR-swizzled LDS (kills the 16-way ds_read_b128 bank conflicts that
// appeared when padding was dropped for global_load_lds). Math unchanged.

__device__ __forceinline__ int fsign(float v)  { return (v > 0.f) - (v < 0.f); }
__device__ __forceinline__ int dsign(double v) { return (v > 0.0) - (v < 0.0); }

typedef int v4i __attribute__((ext_vector_type(4)));

__device__ __forceinline__ void async16(const signed char* g, signed char* l) {
    __builtin_amdgcn_global_load_lds(
        (const __attribute__((address_space(1))) void*)g,
        (__attribute__((address_space(3))) void*)l, 16, 0, 0);
}

// -------- Kernel 1: conv1 dw(3x3,g=3) + pw(1x1 3->128) + sign + maxpool2
// -> pooled1T [n][y16][x16][c128] int8 (c contiguous).
__global__ void k1_conv1(const float* __restrict__ x,
                         const float* __restrict__ w1dw, const float* __restrict__ b1dw,
                         const float* __restrict__ w1pw, const float* __restrict__ b1pw,
                         signed char* __restrict__ pooled1T)
{
    __shared__ float sdw[27], sbdw[3], spw[384], sbpw[128];
    int t = threadIdx.x;
    if (t < 27) sdw[t] = (float)fsign(w1dw[t]);
    if (t < 3)  sbdw[t] = (float)fsign(b1dw[t]);
    for (int i = t; i < 384; i += 256) spw[i] = (float)fsign(w1pw[i]);
    if (t < 128) sbpw[t] = (float)fsign(b1pw[t]);
    __syncthreads();

    int g  = blockIdx.x * 256 + t;
    int px = g & 15, py = (g >> 4) & 15, n = g >> 8;

    double h[3][4];
    const float* xb = x + (size_t)n * 3 * 1024;
    #pragma unroll
    for (int c = 0; c < 3; c++) {
        const float* xc = xb + c * 1024;
        #pragma unroll
        for (int dy = 0; dy < 2; dy++)
        #pragma unroll
        for (int dx = 0; dx < 2; dx++) {
            int y = 2 * py + dy, xx = 2 * px + dx;
            double acc = (double)sbdw[c];
            #pragma unroll
            for (int ky = 0; ky < 3; ky++) {
                int yy = y + ky - 1;
                if (yy < 0 || yy > 31) continue;
                #pragma unroll
                for (int kx = 0; kx < 3; kx++) {
                    int xxx = xx + kx - 1;
                    if (xxx < 0 || xxx > 31) continue;
                    acc += (double)sdw[c * 9 + ky * 3 + kx] * (double)xc[yy * 32 + xxx];
                }
            }
            h[c][dy * 2 + dx] = acc;
        }
    }

    signed char* outb = pooled1T + (size_t)n * 32768 + (py * 16 + px) * 128;
    int cur = 0;
    for (int o = 0; o < 128; o++) {
        double s0 = (double)spw[o * 3 + 0];
        double s1 = (double)spw[o * 3 + 1];
        double s2 = (double)spw[o * 3 + 2];
        double sb = (double)sbpw[o];
        int mx = -2;
        #pragma unroll
        for (int q = 0; q < 4; q++) {
            double p = s0 * h[0][q] + s1 * h[1][q] + s2 * h[2][q] + sb;
            int s = dsign(p);
            mx = s > mx ? s : mx;
        }
        cur |= (mx & 0xff) << ((o & 3) * 8);
        if ((o & 3) == 3) { *(int*)(outb + (o & ~3)) = cur; cur = 0; }
    }
}

// -------- Kernel 2: conv2 dw(3x3, g=128) -> dw2T [n][pos'][c] int8.
// pos' = (py*8+px)*4 + dy*2+dx. XOR trick: prod(+-1) via v^w bit-1 count.
__global__ void k2_dw2(const signed char* __restrict__ pooled1T,
                       const float* __restrict__ w2dw, const float* __restrict__ b2dw,
                       signed char* __restrict__ dw2T)
{
    __shared__ int swt[288];
    __shared__ int sbt[32];
    int t = threadIdx.x;
    for (int i = t; i < 1152; i += 256) {
        int c = i & 127, tap = i >> 7;
        ((signed char*)swt)[tap * 128 + c] = (signed char)fsign(w2dw[c * 9 + tap]);
    }
    if (t < 128) ((signed char*)sbt)[t] = (signed char)fsign(b2dw[t]);
    __syncthreads();

    int b = blockIdx.x;
    int n = b >> 5, pg = b & 31;
    int pos = pg * 8 + (t >> 5);
    int cg = t & 31;
    int y = pos >> 4, x = pos & 15;

    int wv[9];
    #pragma unroll
    for (int tap = 0; tap < 9; tap++) wv[tap] = swt[tap * 32 + cg];

    int cnt = 0;
    const signed char* pb = pooled1T + (size_t)n * 32768;
    #pragma unroll
    for (int ky = 0; ky < 3; ky++) {
        int yy = y + ky - 1;
        if (yy < 0 || yy > 15) continue;
        #pragma unroll
        for (int kx = 0; kx < 3; kx++) {
            int xxx = x + kx - 1;
            if (xxx < 0 || xxx > 15) continue;
            int v = *(const int*)(pb + (yy * 16 + xxx) * 128 + cg * 4);
            int xr = v ^ wv[ky * 3 + kx];
            cnt += (xr >> 1) & 0x01010101;
        }
    }
    int valid = (1 + (y > 0) + (y < 15)) * (1 + (x > 0) + (x < 15));
    int sb = sbt[cg];
    int outv = 0;
    #pragma unroll
    for (int e = 0; e < 4; e++) {
        int cc = (cnt >> (8 * e)) & 0xff;
        int bb = (int)(signed char)((sb >> (8 * e)) & 0xff);
        int val = bb + valid - 2 * cc;
        outv |= (val & 0xff) << (8 * e);
    }
    int py = y >> 1, dy = y & 1, px2 = x >> 1, dx = x & 1;
    int posp = (py * 8 + px2) * 4 + dy * 2 + dx;
    *(int*)(dw2T + (size_t)n * 32768 + posp * 128 + cg * 4) = outv;
}

// -------- Prep: sign tables for conv2-pw B matrix.
__global__ void kprep2(const float* __restrict__ w2pw, const float* __restrict__ b2pw,
                       signed char* __restrict__ w2s, signed char* __restrict__ b2s)
{
    int idx = blockIdx.x * 256 + threadIdx.x;
    float4 w = *(const float4*)(w2pw + (size_t)idx * 4);
    int o = (fsign(w.x) & 0xff) | ((fsign(w.y) & 0xff) << 8)
          | ((fsign(w.z) & 0xff) << 16) | ((fsign(w.w) & 0xff) << 24);
    *(int*)(w2s + (size_t)idx * 4) = o;
    if (idx < 64) {
        float4 bb = ((const float4*)b2pw)[idx];
        int ob = (fsign(bb.x) & 0xff) | ((fsign(bb.y) & 0xff) << 8)
               | ((fsign(bb.z) & 0xff) << 16) | ((fsign(bb.w) & 0xff) << 24);
        *(int*)(b2s + (size_t)idx * 4) = ob;
    }
}

// -------- Kernel 3: conv2 pw as per-sample MFMA GEMM + sign + maxpool -> hT2 [n][16384]
__global__ __launch_bounds__(256) void k3_pw2_mfma(
    const signed char* __restrict__ dw2T, const signed char* __restrict__ w2s,
    const signed char* __restrict__ b2s, signed char* __restrict__ hT2)
{
    __shared__ __align__(16) signed char As[256 * 144];
    __shared__ __align__(16) signed char Bs[64 * 144];
    __shared__ __align__(16) signed char Os[4096];
    int t = threadIdx.x, l = t & 63, wid = t >> 6;
    int n = blockIdx.x;

    const signed char* an = dw2T + (size_t)n * 32768;
    #pragma unroll
    for (int i = 0; i < 8; i++) {
        int row = i * 32 + (t >> 3), seg = (t & 7) * 16;
        *(int4*)&As[row * 144 + seg] = *(const int4*)(an + row * 128 + seg);
    }
    __syncthreads();

    v4i af[4][2];
    #pragma unroll
    for (int i = 0; i < 4; i++)
        #pragma unroll
        for (int ks = 0; ks < 2; ks++)
            af[i][ks] = *(const v4i*)&As[((wid * 4 + i) * 16 + (l & 15)) * 144 + ks * 64 + (l >> 4) * 16];

    for (int oc = 0; oc < 4; oc++) {
        __syncthreads();
        #pragma unroll
        for (int i = 0; i < 2; i++) {
            int row = i * 32 + (t >> 3), seg = (t & 7) * 16;
            *(int4*)&Bs[row * 144 + seg] = *(const int4*)(w2s + (size_t)(oc * 64 + row) * 128 + seg);
        }
        __syncthreads();

        v4i acc[4][4];
        #pragma unroll
        for (int i = 0; i < 4; i++)
            #pragma unroll
            for (int jt = 0; jt < 4; jt++) acc[i][jt] = (v4i){0, 0, 0, 0};

        #pragma unroll
        for (int ks = 0; ks < 2; ks++) {
            v4i bf[4];
            #pragma unroll
            for (int jt = 0; jt < 4; jt++)
                bf[jt] = *(const v4i*)&Bs[(jt * 16 + (l & 15)) * 144 + ks * 64 + (l >> 4) * 16];
            #pragma unroll
            for (int i = 0; i < 4; i++)
                #pragma unroll
                for (int jt = 0; jt < 4; jt++)
                    acc[i][jt] = __builtin_amdgcn_mfma_i32_16x16x64_i8(af[i][ks], bf[jt], acc[i][jt], 0, 0, 0);
        }

        #pragma unroll
        for (int jt = 0; jt < 4; jt++) {
            int o_l = jt * 16 + (l & 15);
            int bia = (int)b2s[oc * 64 + o_l];
            #pragma unroll
            for (int i = 0; i < 4; i++) {
                int mx = -2;
                #pragma unroll
                for (int rr = 0; rr < 4; rr++) {
                    int p = acc[i][jt][rr] + bia;
                    int s = (p > 0) - (p < 0);
                    mx = s > mx ? s : mx;
                }
                int pp = (wid * 4 + i) * 4 + (l >> 4);
                Os[o_l * 64 + pp] = (signed char)mx;
            }
        }
        __syncthreads();
        *(int4*)&hT2[(size_t)n * 16384 + oc * 4096 + t * 16] = *(const int4*)&Os[t * 16];
    }
}

// -------- Prep: fc1_w -> 4 signed radix-128 int8 limbs on 2^-32 grid (exact).
__global__ void kprep(const float* __restrict__ fc1w, signed char* __restrict__ BL)
{
    int t = threadIdx.x;
    int b = blockIdx.x;
    int j = b >> 4, kb = b & 15;
    int k0 = kb * 1024 + t * 4;
    float4 w = *(const float4*)(fc1w + (size_t)j * 16384 + k0);
    float we[4] = {w.x, w.y, w.z, w.w};
    int out[4] = {0, 0, 0, 0};
    #pragma unroll
    for (int e = 0; e < 4; e++) {
        int q = (int)rint((double)we[e] * 4294967296.0);
        q = min(max(q, -266338304), 266338304);
        int d0 = ((q + 64) & 127) - 64; q = (q - d0) >> 7;
        int d1 = ((q + 64) & 127) - 64; q = (q - d1) >> 7;
        int d2 = ((q + 64) & 127) - 64; q = (q - d2) >> 7;
        int d3 = q;
        out[0] |= (d0 & 0xff) << (8 * e);
        out[1] |= (d1 & 0xff) << (8 * e);
        out[2] |= (d2 & 0xff) << (8 * e);
        out[3] |= (d3 & 0xff) << (8 * e);
    }
    #pragma unroll
    for (int m = 0; m < 4; m++)
        *(int*)(BL + (size_t)(j * 4 + m) * 16384 + k0) = out[m];
}

// -------- Kernel 4: fc1 GEMM, 512 thr, double-buffered global_load_lds staging,
// XOR-swizzled LDS: global (row R, seg SG) lives at R*128 + ((SG ^ (R&7))*16).
__global__ __launch_bounds__(512) void k4_fc1_mfma(
    const signed char* __restrict__ hT2, const signed char* __restrict__ BL,
    const float* __restrict__ fc1b, signed char* __restrict__ hs)
{
    __shared__ __align__(16) signed char smem[65536];
    int t = threadIdx.x, l = t & 63, wid = t >> 6;
    int nb0 = blockIdx.y * 128, jb0 = blockIdx.x * 128;
    int wn0 = (wid >> 1) * 32;
    int wj0 = (wid & 1) * 64;

    // staging: lane l -> LDS slot (row l>>3, seg l&7); source global seg (l&7)^(l>>3)
    int srow = l >> 3;
    int sseg = ((l & 7) ^ srow) * 16;
    const signed char* gA = hT2 + (size_t)(nb0 + wid * 16 + srow) * 16384 + sseg;
    const signed char* gB = BL  + (size_t)(jb0 + wid * 16 + srow) * 16384 + sseg;

    v4i acc[2][4];
    #pragma unroll
    for (int i = 0; i < 2; i++)
        #pragma unroll
        for (int q = 0; q < 4; q++) acc[i][q] = (v4i){0, 0, 0, 0};

    {
        signed char* As = smem;
        signed char* Bs = smem + 16384;
        #pragma unroll
        for (int i = 0; i < 2; i++) {
            async16(gA + (size_t)i * 8 * 16384, As + (wid * 16 + i * 8) * 128);
            async16(gB + (size_t)i * 8 * 16384, Bs + (wid * 16 + i * 8) * 128);
        }
    }

    for (int it = 0; it < 128; it++) {
        __syncthreads();
        if (it + 1 < 128) {
            int kt = (it + 1) * 128;
            signed char* As = smem + ((it + 1) & 1) * 32768;
            signed char* Bs = As + 16384;
            #pragma unroll
            for (int i = 0; i < 2; i++) {
                async16(gA + (size_t)i * 8 * 16384 + kt, As + (wid * 16 + i * 8) * 128);
                async16(gB + (size_t)i * 8 * 16384 + kt, Bs + (wid * 16 + i * 8) * 128);
            }
        }
        const signed char* As = smem + (it & 1) * 32768;
        const signed char* Bs = As + 16384;
        #pragma unroll
        for (int ks = 0; ks < 2; ks++) {
            // swizzled segment offset: seg' = (ks*4 + (l>>4)) ^ (l&7)  [row&7 == l&7]
            int sw = (((ks * 4) + (l >> 4)) ^ (l & 7)) * 16;
            v4i af[2], bf[4];
            #pragma unroll
            for (int i = 0; i < 2; i++)
                af[i] = *(const v4i*)&As[(wn0 + i * 16 + (l & 15)) * 128 + sw];
            #pragma unroll
            for (int q = 0; q < 4; q++)
                bf[q] = *(const v4i*)&Bs[(wj0 + q * 16 + (l & 15)) * 128 + sw];
            #pragma unroll
            for (int i = 0; i < 2; i++)
                #pragma unroll
                for (int q = 0; q < 4; q++)
                    acc[i][q] = __builtin_amdgcn_mfma_i32_16x16x64_i8(af[i], bf[q], acc[i][q], 0, 0, 0);
        }
    }

    __syncthreads();
    int* S = (int*)smem;
    #pragma unroll
    for (int i = 0; i < 2; i++)
        #pragma unroll
        for (int q = 0; q < 4; q++)
            #pragma unroll
            for (int rr = 0; rr < 4; rr++) {
                int n_l  = wn0 + i * 16 + (l >> 4) * 4 + rr;
                int jm_l = wj0 + q * 16 + (l & 15);
                S[n_l * 128 + jm_l] = acc[i][q][rr];
            }
    __syncthreads();

    const double SCALE = 1.0 / 4294967296.0;
    #pragma unroll
    for (int i = 0; i < 8; i++) {
        int idx = t * 8 + i;
        int n_l = idx >> 5, j_l = idx & 31;
        int4 s = *(const int4*)&S[n_l * 128 + j_l * 4];
        double val = (double)s.x + 128.0 * (double)s.y
                   + 16384.0 * (double)s.z + 2097152.0 * (double)s.w;
        int j = blockIdx.x * 32 + j_l;
        double p = val * SCALE + (double)fc1b[j];
        hs[(size_t)(nb0 + n_l) * 1024 + j] = (signed char)((p > 0.0) - (p < 0.0));
    }
}

// -------- Kernel 5: fc2, thread per (n,m) output, fp64 accumulate.
__global__ void k5_fc2(const signed char* __restrict__ hs,
                       const float* __restrict__ fc2w, const float* __restrict__ fc2b,
                       float* __restrict__ out)
{
    int idx = blockIdx.x * 256 + threadIdx.x;
    if (idx >= 10240) return;
    int n = idx / 10, m = idx - n * 10;
    const signed char* hr = hs + (size_t)n * 1024;
    const float* wr = fc2w + (size_t)m * 1024;
    double acc = (double)fc2b[m];
    for (int jb = 0; jb < 1024; jb += 16) {
        int4 hv = *(const int4*)(hr + jb);
        int wd[4] = {hv.x, hv.y, hv.z, hv.w};
        #pragma unroll
        for (int u = 0; u < 4; u++)
            #pragma unroll
            for (int e = 0; e < 4; e++)
                acc += (double)(signed char)(wd[u] >> (8 * e)) * (double)wr[jb + u * 4 + e];
    }
    out[idx] = (float)acc;
}

extern "C" void kernel_launch(void* const* d_in, const int* in_sizes, int n_in,
                              void* d_out, int out_size, void* d_ws, size_t ws_size,
                              hipStream_t stream)
{
    const float* x    = (const float*)d_in[0];
    const float* w1dw = (const float*)d_in[1];
    const float* b1dw = (const float*)d_in[2];
    const float* w1pw = (const float*)d_in[3];
    const float* b1pw = (const float*)d_in[4];
    const float* w2dw = (const float*)d_in[5];
    const float* b2dw = (const float*)d_in[6];
    const float* w2pw = (const float*)d_in[7];
    const float* b2pw = (const float*)d_in[8];
    const float* fc1w = (const float*)d_in[9];
    const float* fc1b = (const float*)d_in[10];
    const float* fc2w = (const float*)d_in[11];
    const float* fc2b = (const float*)d_in[12];
    float* out = (float*)d_out;

    char* ws = (char*)d_ws;
    signed char* pooled1T = (signed char*)(ws);
    signed char* dw2T     = (signed char*)(ws + 33554432);
    signed char* hT2      = (signed char*)(ws + 67108864);
    signed char* w2s      = (signed char*)(ws + 83886080);
    signed char* b2s      = (signed char*)(ws + 83886080 + 32768);
    signed char* BL       = (signed char*)(ws);
    signed char* hs       = (signed char*)(ws + 83886080);

    hipLaunchKernelGGL(k1_conv1,    dim3(1024),  dim3(256), 0, stream,
                       x, w1dw, b1dw, w1pw, b1pw, pooled1T);
    hipLaunchKernelGGL(k2_dw2,      dim3(32768), dim3(256), 0, stream,
                       pooled1T, w2dw, b2dw, dw2T);
    hipLaunchKernelGGL(kprep2,      dim3(32),    dim3(256), 0, stream,
                       w2pw, b2pw, w2s, b2s);
    hipLaunchKernelGGL(k3_pw2_mfma, dim3(1024),  dim3(256), 0, stream,
                       dw2T, w2s, b2s, hT2);
    hipLaunchKernelGGL(kprep,       dim3(16384), dim3(256), 0, stream,
                       fc1w, BL);
    hipLaunchKernelGGL(k4_fc1_mfma, dim3(32, 8), dim3(512), 0, stream,
                       hT2, BL, fc1b, hs);
    hipLaunchKernelGGL(k5_fc2,      dim3(40),    dim3(256), 0, stream,
                       hs, fc2w, fc2b, out);
}

// Round 6
// 393.475 us; speedup vs baseline: 7.2949x; 1.0806x over previous
//
#include <hip/hip_runtime.h>

// BinaryConnectNet forward.
// R6: k2 (depthwise conv2) fused into k3's A-fragment build via packed-byte
// XOR-popcount with +32 offset encoding (corrected in epilogue through b2adj).
// dw2T tensor and its 67MB round-trip eliminated. k5 regridded.

__device__ __forceinline__ int fsign(float v)  { return (v > 0.f) - (v < 0.f); }
__device__ __forceinline__ int dsign(double v) { return (v > 0.0) - (v < 0.0); }

typedef int v4i __attribute__((ext_vector_type(4)));

__device__ __forceinline__ void async16(const signed char* g, signed char* l) {
    __builtin_amdgcn_global_load_lds(
        (const __attribute__((address_space(1))) void*)g,
        (__attribute__((address_space(3))) void*)l, 16, 0, 0);
}

// -------- Kernel 1: conv1 dw(3x3,g=3) + pw(1x1 3->128) + sign + maxpool2
// -> pooled1T [n][y16][x16][c128] int8 (c contiguous).
__global__ void k1_conv1(const float* __restrict__ x,
                         const float* __restrict__ w1dw, const float* __restrict__ b1dw,
                         const float* __restrict__ w1pw, const float* __restrict__ b1pw,
                         signed char* __restrict__ pooled1T)
{
    __shared__ float sdw[27], sbdw[3], spw[384], sbpw[128];
    int t = threadIdx.x;
    if (t < 27) sdw[t] = (float)fsign(w1dw[t]);
    if (t < 3)  sbdw[t] = (float)fsign(b1dw[t]);
    for (int i = t; i < 384; i += 256) spw[i] = (float)fsign(w1pw[i]);
    if (t < 128) sbpw[t] = (float)fsign(b1pw[t]);
    __syncthreads();

    int g  = blockIdx.x * 256 + t;
    int px = g & 15, py = (g >> 4) & 15, n = g >> 8;

    double h[3][4];
    const float* xb = x + (size_t)n * 3 * 1024;
    #pragma unroll
    for (int c = 0; c < 3; c++) {
        const float* xc = xb + c * 1024;
        #pragma unroll
        for (int dy = 0; dy < 2; dy++)
        #pragma unroll
        for (int dx = 0; dx < 2; dx++) {
            int y = 2 * py + dy, xx = 2 * px + dx;
            double acc = (double)sbdw[c];
            #pragma unroll
            for (int ky = 0; ky < 3; ky++) {
                int yy = y + ky - 1;
                if (yy < 0 || yy > 31) continue;
                #pragma unroll
                for (int kx = 0; kx < 3; kx++) {
                    int xxx = xx + kx - 1;
                    if (xxx < 0 || xxx > 31) continue;
                    acc += (double)sdw[c * 9 + ky * 3 + kx] * (double)xc[yy * 32 + xxx];
                }
            }
            h[c][dy * 2 + dx] = acc;
        }
    }

    signed char* outb = pooled1T + (size_t)n * 32768 + (py * 16 + px) * 128;
    int cur = 0;
    for (int o = 0; o < 128; o++) {
        double s0 = (double)spw[o * 3 + 0];
        double s1 = (double)spw[o * 3 + 1];
        double s2 = (double)spw[o * 3 + 2];
        double sb = (double)sbpw[o];
        int mx = -2;
        #pragma unroll
        for (int q = 0; q < 4; q++) {
            double p = s0 * h[0][q] + s1 * h[1][q] + s2 * h[2][q] + sb;
            int s = dsign(p);
            mx = s > mx ? s : mx;
        }
        cur |= (mx & 0xff) << ((o & 3) * 8);
        if ((o & 3) == 3) { *(int*)(outb + (o & ~3)) = cur; cur = 0; }
    }
}

// -------- Prep: conv2-pw sign matrix + adjusted bias b2adj[o] = sign(b)-32*rowsum.
__global__ void kprep2(const float* __restrict__ w2pw, const float* __restrict__ b2pw,
                       signed char* __restrict__ w2s, int* __restrict__ b2adj)
{
    int o = blockIdx.x * 64 + threadIdx.x;   // 256
    int rs = 0;
    for (int cq = 0; cq < 32; cq++) {
        float4 w = *(const float4*)(w2pw + (size_t)o * 128 + cq * 4);
        int s0 = fsign(w.x), s1 = fsign(w.y), s2 = fsign(w.z), s3 = fsign(w.w);
        rs += s0 + s1 + s2 + s3;
        int pk = (s0 & 0xff) | ((s1 & 0xff) << 8) | ((s2 & 0xff) << 16) | ((s3 & 0xff) << 24);
        *(int*)(w2s + (size_t)o * 128 + cq * 4) = pk;
    }
    b2adj[o] = fsign(b2pw[o]) - 32 * rs;
}

// -------- Kernel 3 (fused): depthwise conv2 + pointwise MFMA GEMM + sign + maxpool
// -> hT2 [n][16384]. A-fragments computed on the fly from pooled1T:
// af byte = dw_val + 32 (always in [22,42]); epilogue corrects via b2adj.
__global__ __launch_bounds__(256) void k3_fused(
    const signed char* __restrict__ pooled1T,
    const float* __restrict__ w2dw, const float* __restrict__ b2dw,
    const signed char* __restrict__ w2s, const int* __restrict__ b2adj,
    signed char* __restrict__ hT2)
{
    __shared__ __align__(16) signed char sw4[1152];   // [tap][c] signs 0x01/0xff
    __shared__ __align__(16) signed char sdb2[128];   // bias+1 per c (0x00/0x02)
    __shared__ int sb2adj[256];
    __shared__ __align__(16) signed char Bs[64 * 144];
    __shared__ __align__(16) signed char Os[4096];

    int t = threadIdx.x, l = t & 63, wid = t >> 6;
    int n = blockIdx.x;

    for (int i = t; i < 1152; i += 256) {
        int c = i & 127, tap = i >> 7;
        sw4[tap * 128 + c] = (signed char)fsign(w2dw[c * 9 + tap]);
    }
    if (t < 128) sdb2[t] = (signed char)(fsign(b2dw[t]) + 1);
    if (t < 256) sb2adj[t] = b2adj[t];
    __syncthreads();

    const signed char* pb = pooled1T + (size_t)n * 32768;
    int frow = l & 15;

    v4i af[4][2];
    #pragma unroll
    for (int ks = 0; ks < 2; ks++) {
        int c0 = ks * 64 + (l >> 4) * 16;
        int4 w4[9];
        #pragma unroll
        for (int tap = 0; tap < 9; tap++)
            w4[tap] = *(const int4*)&sw4[tap * 128 + c0];
        int4 sdbv = *(const int4*)&sdb2[c0];

        #pragma unroll
        for (int i = 0; i < 4; i++) {
            int r = (wid * 4 + i) * 16 + frow;          // pos'
            int py = r >> 5, px2 = (r >> 2) & 7, dy = (r >> 1) & 1, dx = r & 1;
            int y = 2 * py + dy, x = 2 * px2 + dx;
            int4 cnt = (int4){0, 0, 0, 0};
            #pragma unroll
            for (int ky = 0; ky < 3; ky++) {
                int yy = y + ky - 1;
                int yc = min(max(yy, 0), 15);
                #pragma unroll
                for (int kx = 0; kx < 3; kx++) {
                    int xx2 = x + kx - 1;
                    int xc = min(max(xx2, 0), 15);
                    int inb = ((yy == yc) && (xx2 == xc)) ? 0x01010101 : 0;
                    int4 v = *(const int4*)(pb + (yc * 16 + xc) * 128 + c0);
                    int4 w = w4[ky * 3 + kx];
                    cnt.x += ((v.x ^ w.x) >> 1) & inb;
                    cnt.y += ((v.y ^ w.y) >> 1) & inb;
                    cnt.z += ((v.z ^ w.z) >> 1) & inb;
                    cnt.w += ((v.w ^ w.w) >> 1) & inb;
                }
            }
            int valid = (1 + (y > 0) + (y < 15)) * (1 + (x > 0) + (x < 15));
            int mb = (valid + 31) * 0x01010101;
            int4 u;
            u.x = sdbv.x + mb - (cnt.x + cnt.x);
            u.y = sdbv.y + mb - (cnt.y + cnt.y);
            u.z = sdbv.z + mb - (cnt.z + cnt.z);
            u.w = sdbv.w + mb - (cnt.w + cnt.w);
            af[i][ks] = (v4i){u.x, u.y, u.z, u.w};
        }
    }

    for (int oc = 0; oc < 4; oc++) {
        __syncthreads();
        #pragma unroll
        for (int i = 0; i < 2; i++) {
            int row = i * 32 + (t >> 3), seg = (t & 7) * 16;
            *(int4*)&Bs[row * 144 + seg] = *(const int4*)(w2s + (size_t)(oc * 64 + row) * 128 + seg);
        }
        __syncthreads();

        v4i acc[4][4];
        #pragma unroll
        for (int i = 0; i < 4; i++)
            #pragma unroll
            for (int jt = 0; jt < 4; jt++) acc[i][jt] = (v4i){0, 0, 0, 0};

        #pragma unroll
        for (int ks = 0; ks < 2; ks++) {
            v4i bf[4];
            #pragma unroll
            for (int jt = 0; jt < 4; jt++)
                bf[jt] = *(const v4i*)&Bs[(jt * 16 + frow) * 144 + ks * 64 + (l >> 4) * 16];
            #pragma unroll
            for (int i = 0; i < 4; i++)
                #pragma unroll
                for (int jt = 0; jt < 4; jt++)
                    acc[i][jt] = __builtin_amdgcn_mfma_i32_16x16x64_i8(af[i][ks], bf[jt], acc[i][jt], 0, 0, 0);
        }

        #pragma unroll
        for (int jt = 0; jt < 4; jt++) {
            int o_l = jt * 16 + frow;
            int bia = sb2adj[oc * 64 + o_l];
            #pragma unroll
            for (int i = 0; i < 4; i++) {
                int mx = -2;
                #pragma unroll
                for (int rr = 0; rr < 4; rr++) {
                    int p = acc[i][jt][rr] + bia;
                    int s = (p > 0) - (p < 0);
                    mx = s > mx ? s : mx;
                }
                int pp = (wid * 4 + i) * 4 + (l >> 4);
                Os[o_l * 64 + pp] = (signed char)mx;
            }
        }
        __syncthreads();
        *(int4*)&hT2[(size_t)n * 16384 + oc * 4096 + t * 16] = *(const int4*)&Os[t * 16];
    }
}

// -------- Prep: fc1_w -> 4 signed radix-128 int8 limbs on 2^-32 grid (exact).
__global__ void kprep(const float* __restrict__ fc1w, signed char* __restrict__ BL)
{
    int t = threadIdx.x;
    int b = blockIdx.x;
    int j = b >> 4, kb = b & 15;
    int k0 = kb * 1024 + t * 4;
    float4 w = *(const float4*)(fc1w + (size_t)j * 16384 + k0);
    float we[4] = {w.x, w.y, w.z, w.w};
    int out[4] = {0, 0, 0, 0};
    #pragma unroll
    for (int e = 0; e < 4; e++) {
        int q = (int)rint((double)we[e] * 4294967296.0);
        q = min(max(q, -266338304), 266338304);
        int d0 = ((q + 64) & 127) - 64; q = (q - d0) >> 7;
        int d1 = ((q + 64) & 127) - 64; q = (q - d1) >> 7;
        int d2 = ((q + 64) & 127) - 64; q = (q - d2) >> 7;
        int d3 = q;
        out[0] |= (d0 & 0xff) << (8 * e);
        out[1] |= (d1 & 0xff) << (8 * e);
        out[2] |= (d2 & 0xff) << (8 * e);
        out[3] |= (d3 & 0xff) << (8 * e);
    }
    #pragma unroll
    for (int m = 0; m < 4; m++)
        *(int*)(BL + (size_t)(j * 4 + m) * 16384 + k0) = out[m];
}

// -------- Kernel 4: fc1 GEMM, 512 thr, double-buffered global_load_lds staging,
// XOR-swizzled LDS: global (row R, seg SG) lives at R*128 + ((SG ^ (R&7))*16).
__global__ __launch_bounds__(512) void k4_fc1_mfma(
    const signed char* __restrict__ hT2, const signed char* __restrict__ BL,
    const float* __restrict__ fc1b, signed char* __restrict__ hs)
{
    __shared__ __align__(16) signed char smem[65536];
    int t = threadIdx.x, l = t & 63, wid = t >> 6;
    int nb0 = blockIdx.y * 128, jb0 = blockIdx.x * 128;
    int wn0 = (wid >> 1) * 32;
    int wj0 = (wid & 1) * 64;

    int srow = l >> 3;
    int sseg = ((l & 7) ^ srow) * 16;
    const signed char* gA = hT2 + (size_t)(nb0 + wid * 16 + srow) * 16384 + sseg;
    const signed char* gB = BL  + (size_t)(jb0 + wid * 16 + srow) * 16384 + sseg;

    v4i acc[2][4];
    #pragma unroll
    for (int i = 0; i < 2; i++)
        #pragma unroll
        for (int q = 0; q < 4; q++) acc[i][q] = (v4i){0, 0, 0, 0};

    {
        signed char* As = smem;
        signed char* Bs = smem + 16384;
        #pragma unroll
        for (int i = 0; i < 2; i++) {
            async16(gA + (size_t)i * 8 * 16384, As + (wid * 16 + i * 8) * 128);
            async16(gB + (size_t)i * 8 * 16384, Bs + (wid * 16 + i * 8) * 128);
        }
    }

    for (int it = 0; it < 128; it++) {
        __syncthreads();
        if (it + 1 < 128) {
            int kt = (it + 1) * 128;
            signed char* As = smem + ((it + 1) & 1) * 32768;
            signed char* Bs = As + 16384;
            #pragma unroll
            for (int i = 0; i < 2; i++) {
                async16(gA + (size_t)i * 8 * 16384 + kt, As + (wid * 16 + i * 8) * 128);
                async16(gB + (size_t)i * 8 * 16384 + kt, Bs + (wid * 16 + i * 8) * 128);
            }
        }
        const signed char* As = smem + (it & 1) * 32768;
        const signed char* Bs = As + 16384;
        #pragma unroll
        for (int ks = 0; ks < 2; ks++) {
            int sw = (((ks * 4) + (l >> 4)) ^ (l & 7)) * 16;
            v4i af[2], bf[4];
            #pragma unroll
            for (int i = 0; i < 2; i++)
                af[i] = *(const v4i*)&As[(wn0 + i * 16 + (l & 15)) * 128 + sw];
            #pragma unroll
            for (int q = 0; q < 4; q++)
                bf[q] = *(const v4i*)&Bs[(wj0 + q * 16 + (l & 15)) * 128 + sw];
            #pragma unroll
            for (int i = 0; i < 2; i++)
                #pragma unroll
                for (int q = 0; q < 4; q++)
                    acc[i][q] = __builtin_amdgcn_mfma_i32_16x16x64_i8(af[i], bf[q], acc[i][q], 0, 0, 0);
        }
    }

    __syncthreads();
    int* S = (int*)smem;
    #pragma unroll
    for (int i = 0; i < 2; i++)
        #pragma unroll
        for (int q = 0; q < 4; q++)
            #pragma unroll
            for (int rr = 0; rr < 4; rr++) {
                int n_l  = wn0 + i * 16 + (l >> 4) * 4 + rr;
                int jm_l = wj0 + q * 16 + (l & 15);
                S[n_l * 128 + jm_l] = acc[i][q][rr];
            }
    __syncthreads();

    const double SCALE = 1.0 / 4294967296.0;
    #pragma unroll
    for (int i = 0; i < 8; i++) {
        int idx = t * 8 + i;
        int n_l = idx >> 5, j_l = idx & 31;
        int4 s = *(const int4*)&S[n_l * 128 + j_l * 4];
        double val = (double)s.x + 128.0 * (double)s.y
                   + 16384.0 * (double)s.z + 2097152.0 * (double)s.w;
        int j = blockIdx.x * 32 + j_l;
        double p = val * SCALE + (double)fc1b[j];
        hs[(size_t)(nb0 + n_l) * 1024 + j] = (signed char)((p > 0.0) - (p < 0.0));
    }
}

// -------- Kernel 5: fc2, thread per (n,m) output, fp64 accumulate.
__global__ void k5_fc2(const signed char* __restrict__ hs,
                       const float* __restrict__ fc2w, const float* __restrict__ fc2b,
                       float* __restrict__ out)
{
    int idx = blockIdx.x * 64 + threadIdx.x;
    if (idx >= 10240) return;
    int n = idx / 10, m = idx - n * 10;
    const signed char* hr = hs + (size_t)n * 1024;
    const float* wr = fc2w + (size_t)m * 1024;
    double acc = (double)fc2b[m];
    for (int jb = 0; jb < 1024; jb += 16) {
        int4 hv = *(const int4*)(hr + jb);
        int wd[4] = {hv.x, hv.y, hv.z, hv.w};
        #pragma unroll
        for (int u = 0; u < 4; u++)
            #pragma unroll
            for (int e = 0; e < 4; e++)
                acc += (double)(signed char)(wd[u] >> (8 * e)) * (double)wr[jb + u * 4 + e];
    }
    out[idx] = (float)acc;
}

extern "C" void kernel_launch(void* const* d_in, const int* in_sizes, int n_in,
                              void* d_out, int out_size, void* d_ws, size_t ws_size,
                              hipStream_t stream)
{
    const float* x    = (const float*)d_in[0];
    const float* w1dw = (const float*)d_in[1];
    const float* b1dw = (const float*)d_in[2];
    const float* w1pw = (const float*)d_in[3];
    const float* b1pw = (const float*)d_in[4];
    const float* w2dw = (const float*)d_in[5];
    const float* b2dw = (const float*)d_in[6];
    const float* w2pw = (const float*)d_in[7];
    const float* b2pw = (const float*)d_in[8];
    const float* fc1w = (const float*)d_in[9];
    const float* fc1b = (const float*)d_in[10];
    const float* fc2w = (const float*)d_in[11];
    const float* fc2b = (const float*)d_in[12];
    float* out = (float*)d_out;

    // workspace:
    //   pooled1T @0        33.5MB  (dead after k3_fused)
    //   BL       @0        64MiB   (written by kprep after k3_fused)
    //   hT2      @64MiB    16MiB
    //   w2s      @80MiB    32KB ; b2adj @80MiB+32KB 1KB  (dead after k3_fused)
    //   hs       @80MiB    1MiB   (written by k4 after k3 done)
    char* ws = (char*)d_ws;
    signed char* pooled1T = (signed char*)(ws);
    signed char* hT2      = (signed char*)(ws + 67108864);
    signed char* w2s      = (signed char*)(ws + 83886080);
    int*         b2adj    = (int*)(ws + 83886080 + 32768);
    signed char* BL       = (signed char*)(ws);
    signed char* hs       = (signed char*)(ws + 83886080);

    hipLaunchKernelGGL(k1_conv1,  dim3(1024),  dim3(256), 0, stream,
                       x, w1dw, b1dw, w1pw, b1pw, pooled1T);
    hipLaunchKernelGGL(kprep2,    dim3(4),     dim3(64),  0, stream,
                       w2pw, b2pw, w2s, b2adj);
    hipLaunchKernelGGL(k3_fused,  dim3(1024),  dim3(256), 0, stream,
                       pooled1T, w2dw, b2dw, w2s, b2adj, hT2);
    hipLaunchKernelGGL(kprep,     dim3(16384), dim3(256), 0, stream,
                       fc1w, BL);
    hipLaunchKernelGGL(k4_fc1_mfma, dim3(32, 8), dim3(512), 0, stream,
                       hT2, BL, fc1b, hs);
    hipLaunchKernelGGL(k5_fc2,    dim3(160),   dim3(64),  0, stream,
                       hs, fc2w, fc2b, out);
}

// Round 7
// 373.208 us; speedup vs baseline: 7.6910x; 1.0543x over previous
//
#include <hip/hip_runtime.h>

// BinaryConnectNet forward.
// R7: k3_fused data-motion rework — pooled sample staged in LDS once
// (coalesced, XOR-swizzled), B-frags direct from global, Os padded to 80B.
// Math identical to R6 (offset encoding verified).

__device__ __forceinline__ int fsign(float v)  { return (v > 0.f) - (v < 0.f); }
__device__ __forceinline__ int dsign(double v) { return (v > 0.0) - (v < 0.0); }

typedef int v4i __attribute__((ext_vector_type(4)));

__device__ __forceinline__ void async16(const signed char* g, signed char* l) {
    __builtin_amdgcn_global_load_lds(
        (const __attribute__((address_space(1))) void*)g,
        (__attribute__((address_space(3))) void*)l, 16, 0, 0);
}

// -------- Kernel 1: conv1 dw(3x3,g=3) + pw(1x1 3->128) + sign + maxpool2
// -> pooled1T [n][y16][x16][c128] int8 (c contiguous).
__global__ void k1_conv1(const float* __restrict__ x,
                         const float* __restrict__ w1dw, const float* __restrict__ b1dw,
                         const float* __restrict__ w1pw, const float* __restrict__ b1pw,
                         signed char* __restrict__ pooled1T)
{
    __shared__ float sdw[27], sbdw[3], spw[384], sbpw[128];
    int t = threadIdx.x;
    if (t < 27) sdw[t] = (float)fsign(w1dw[t]);
    if (t < 3)  sbdw[t] = (float)fsign(b1dw[t]);
    for (int i = t; i < 384; i += 256) spw[i] = (float)fsign(w1pw[i]);
    if (t < 128) sbpw[t] = (float)fsign(b1pw[t]);
    __syncthreads();

    int g  = blockIdx.x * 256 + t;
    int px = g & 15, py = (g >> 4) & 15, n = g >> 8;

    double h[3][4];
    const float* xb = x + (size_t)n * 3 * 1024;
    #pragma unroll
    for (int c = 0; c < 3; c++) {
        const float* xc = xb + c * 1024;
        #pragma unroll
        for (int dy = 0; dy < 2; dy++)
        #pragma unroll
        for (int dx = 0; dx < 2; dx++) {
            int y = 2 * py + dy, xx = 2 * px + dx;
            double acc = (double)sbdw[c];
            #pragma unroll
            for (int ky = 0; ky < 3; ky++) {
                int yy = y + ky - 1;
                if (yy < 0 || yy > 31) continue;
                #pragma unroll
                for (int kx = 0; kx < 3; kx++) {
                    int xxx = xx + kx - 1;
                    if (xxx < 0 || xxx > 31) continue;
                    acc += (double)sdw[c * 9 + ky * 3 + kx] * (double)xc[yy * 32 + xxx];
                }
            }
            h[c][dy * 2 + dx] = acc;
        }
    }

    signed char* outb = pooled1T + (size_t)n * 32768 + (py * 16 + px) * 128;
    int cur = 0;
    for (int o = 0; o < 128; o++) {
        double s0 = (double)spw[o * 3 + 0];
        double s1 = (double)spw[o * 3 + 1];
        double s2 = (double)spw[o * 3 + 2];
        double sb = (double)sbpw[o];
        int mx = -2;
        #pragma unroll
        for (int q = 0; q < 4; q++) {
            double p = s0 * h[0][q] + s1 * h[1][q] + s2 * h[2][q] + sb;
            int s = dsign(p);
            mx = s > mx ? s : mx;
        }
        cur |= (mx & 0xff) << ((o & 3) * 8);
        if ((o & 3) == 3) { *(int*)(outb + (o & ~3)) = cur; cur = 0; }
    }
}

// -------- Prep: conv2-pw sign matrix + adjusted bias b2adj[o] = sign(b)-32*rowsum.
__global__ void kprep2(const float* __restrict__ w2pw, const float* __restrict__ b2pw,
                       signed char* __restrict__ w2s, int* __restrict__ b2adj)
{
    int o = blockIdx.x * 64 + threadIdx.x;   // 256
    int rs = 0;
    for (int cq = 0; cq < 32; cq++) {
        float4 w = *(const float4*)(w2pw + (size_t)o * 128 + cq * 4);
        int s0 = fsign(w.x), s1 = fsign(w.y), s2 = fsign(w.z), s3 = fsign(w.w);
        rs += s0 + s1 + s2 + s3;
        int pk = (s0 & 0xff) | ((s1 & 0xff) << 8) | ((s2 & 0xff) << 16) | ((s3 & 0xff) << 24);
        *(int*)(w2s + (size_t)o * 128 + cq * 4) = pk;
    }
    b2adj[o] = fsign(b2pw[o]) - 32 * rs;
}

// -------- Kernel 3 (fused): depthwise conv2 + pointwise MFMA GEMM + sign + maxpool
// -> hT2 [n][16384]. Pooled sample staged in LDS (XOR-swizzled 16B chunks);
// A-frag byte = dw_val + 32; epilogue corrects via b2adj.
__global__ __launch_bounds__(256, 3) void k3_fused(
    const signed char* __restrict__ pooled1T,
    const float* __restrict__ w2dw, const float* __restrict__ b2dw,
    const signed char* __restrict__ w2s, const int* __restrict__ b2adj,
    signed char* __restrict__ hT2)
{
    __shared__ __align__(16) signed char Ps[32768];   // pooled sample, swizzled
    __shared__ __align__(16) signed char sw4[1152];   // [tap][c] signs
    __shared__ __align__(16) signed char sdb2[128];   // sign(b2dw)+1 per c
    __shared__ int sb2adj[256];
    __shared__ __align__(16) signed char Os[64 * 80]; // padded epilogue buffer

    int t = threadIdx.x, l = t & 63, wid = t >> 6;
    int n = blockIdx.x;
    const signed char* pb = pooled1T + (size_t)n * 32768;

    // stage sample: coalesced global reads, swizzled LDS writes
    #pragma unroll
    for (int it = 0; it < 8; it++) {
        int off = it * 4096 + t * 16;
        int p = off >> 7, seg = (off >> 4) & 7;
        *(int4*)&Ps[p * 128 + ((seg ^ (p & 7)) * 16)] = *(const int4*)(pb + off);
    }
    for (int i = t; i < 1152; i += 256) {
        int c = i & 127, tap = i >> 7;
        sw4[tap * 128 + c] = (signed char)fsign(w2dw[c * 9 + tap]);
    }
    if (t < 128) sdb2[t] = (signed char)(fsign(b2dw[t]) + 1);
    if (t < 256) sb2adj[t] = b2adj[t];
    __syncthreads();

    int frow = l & 15;

    v4i af[4][2];
    #pragma unroll
    for (int ks = 0; ks < 2; ks++) {
        int c0 = ks * 64 + (l >> 4) * 16;
        int cc = c0 >> 4;                         // chunk index 0..7
        int4 w4[9];
        #pragma unroll
        for (int tap = 0; tap < 9; tap++)
            w4[tap] = *(const int4*)&sw4[tap * 128 + c0];
        int4 sdbv = *(const int4*)&sdb2[c0];

        #pragma unroll
        for (int i = 0; i < 4; i++) {
            int r = (wid * 4 + i) * 16 + frow;    // pos'
            int py = r >> 5, px2 = (r >> 2) & 7, dy = (r >> 1) & 1, dx = r & 1;
            int y = 2 * py + dy, x = 2 * px2 + dx;
            int4 cnt = (int4){0, 0, 0, 0};
            #pragma unroll
            for (int ky = 0; ky < 3; ky++) {
                int yy = y + ky - 1;
                int yc = min(max(yy, 0), 15);
                #pragma unroll
                for (int kx = 0; kx < 3; kx++) {
                    int xx2 = x + kx - 1;
                    int xc = min(max(xx2, 0), 15);
                    int inb = ((yy == yc) && (xx2 == xc)) ? 0x01010101 : 0;
                    int p = yc * 16 + xc;
                    int4 v = *(const int4*)&Ps[p * 128 + ((cc ^ (p & 7)) * 16)];
                    int4 w = w4[ky * 3 + kx];
                    cnt.x += ((v.x ^ w.x) >> 1) & inb;
                    cnt.y += ((v.y ^ w.y) >> 1) & inb;
                    cnt.z += ((v.z ^ w.z) >> 1) & inb;
                    cnt.w += ((v.w ^ w.w) >> 1) & inb;
                }
            }
            int valid = (1 + (y > 0) + (y < 15)) * (1 + (x > 0) + (x < 15));
            int mb = (valid + 31) * 0x01010101;
            int4 u;
            u.x = sdbv.x + mb - (cnt.x + cnt.x);
            u.y = sdbv.y + mb - (cnt.y + cnt.y);
            u.z = sdbv.z + mb - (cnt.z + cnt.z);
            u.w = sdbv.w + mb - (cnt.w + cnt.w);
            af[i][ks] = (v4i){u.x, u.y, u.z, u.w};
        }
    }

    for (int oc = 0; oc < 4; oc++) {
        v4i acc[4][4];
        #pragma unroll
        for (int i = 0; i < 4; i++)
            #pragma unroll
            for (int jt = 0; jt < 4; jt++) acc[i][jt] = (v4i){0, 0, 0, 0};

        #pragma unroll
        for (int ks = 0; ks < 2; ks++) {
            v4i bf[4];
            #pragma unroll
            for (int jt = 0; jt < 4; jt++)
                bf[jt] = *(const v4i*)(w2s + (size_t)(oc * 64 + jt * 16 + frow) * 128
                                       + ks * 64 + (l >> 4) * 16);
            #pragma unroll
            for (int i = 0; i < 4; i++)
                #pragma unroll
                for (int jt = 0; jt < 4; jt++)
                    acc[i][jt] = __builtin_amdgcn_mfma_i32_16x16x64_i8(af[i][ks], bf[jt], acc[i][jt], 0, 0, 0);
        }

        __syncthreads();   // previous oc's Os copy complete
        #pragma unroll
        for (int jt = 0; jt < 4; jt++) {
            int o_l = jt * 16 + frow;
            int bia = sb2adj[oc * 64 + o_l];
            #pragma unroll
            for (int i = 0; i < 4; i++) {
                int mx = -2;
                #pragma unroll
                for (int rr = 0; rr < 4; rr++) {
                    int p = acc[i][jt][rr] + bia;
                    int s = (p > 0) - (p < 0);
                    mx = s > mx ? s : mx;
                }
                int pp = (wid * 4 + i) * 4 + (l >> 4);
                Os[o_l * 80 + pp] = (signed char)mx;
            }
        }
        __syncthreads();
        *(int4*)&hT2[(size_t)n * 16384 + oc * 4096 + t * 16]
            = *(const int4*)&Os[(t >> 2) * 80 + (t & 3) * 16];
    }
}

// -------- Prep: fc1_w -> 4 signed radix-128 int8 limbs on 2^-32 grid (exact).
__global__ void kprep(const float* __restrict__ fc1w, signed char* __restrict__ BL)
{
    int t = threadIdx.x;
    int b = blockIdx.x;
    int j = b >> 4, kb = b & 15;
    int k0 = kb * 1024 + t * 4;
    float4 w = *(const float4*)(fc1w + (size_t)j * 16384 + k0);
    float we[4] = {w.x, w.y, w.z, w.w};
    int out[4] = {0, 0, 0, 0};
    #pragma unroll
    for (int e = 0; e < 4; e++) {
        int q = (int)rint((double)we[e] * 4294967296.0);
        q = min(max(q, -266338304), 266338304);
        int d0 = ((q + 64) & 127) - 64; q = (q - d0) >> 7;
        int d1 = ((q + 64) & 127) - 64; q = (q - d1) >> 7;
        int d2 = ((q + 64) & 127) - 64; q = (q - d2) >> 7;
        int d3 = q;
        out[0] |= (d0 & 0xff) << (8 * e);
        out[1] |= (d1 & 0xff) << (8 * e);
        out[2] |= (d2 & 0xff) << (8 * e);
        out[3] |= (d3 & 0xff) << (8 * e);
    }
    #pragma unroll
    for (int m = 0; m < 4; m++)
        *(int*)(BL + (size_t)(j * 4 + m) * 16384 + k0) = out[m];
}

// -------- Kernel 4: fc1 GEMM, 512 thr, double-buffered global_load_lds staging,
// XOR-swizzled LDS: global (row R, seg SG) lives at R*128 + ((SG ^ (R&7))*16).
__global__ __launch_bounds__(512) void k4_fc1_mfma(
    const signed char* __restrict__ hT2, const signed char* __restrict__ BL,
    const float* __restrict__ fc1b, signed char* __restrict__ hs)
{
    __shared__ __align__(16) signed char smem[65536];
    int t = threadIdx.x, l = t & 63, wid = t >> 6;
    int nb0 = blockIdx.y * 128, jb0 = blockIdx.x * 128;
    int wn0 = (wid >> 1) * 32;
    int wj0 = (wid & 1) * 64;

    int srow = l >> 3;
    int sseg = ((l & 7) ^ srow) * 16;
    const signed char* gA = hT2 + (size_t)(nb0 + wid * 16 + srow) * 16384 + sseg;
    const signed char* gB = BL  + (size_t)(jb0 + wid * 16 + srow) * 16384 + sseg;

    v4i acc[2][4];
    #pragma unroll
    for (int i = 0; i < 2; i++)
        #pragma unroll
        for (int q = 0; q < 4; q++) acc[i][q] = (v4i){0, 0, 0, 0};

    {
        signed char* As = smem;
        signed char* Bs = smem + 16384;
        #pragma unroll
        for (int i = 0; i < 2; i++) {
            async16(gA + (size_t)i * 8 * 16384, As + (wid * 16 + i * 8) * 128);
            async16(gB + (size_t)i * 8 * 16384, Bs + (wid * 16 + i * 8) * 128);
        }
    }

    for (int it = 0; it < 128; it++) {
        __syncthreads();
        if (it + 1 < 128) {
            int kt = (it + 1) * 128;
            signed char* As = smem + ((it + 1) & 1) * 32768;
            signed char* Bs = As + 16384;
            #pragma unroll
            for (int i = 0; i < 2; i++) {
                async16(gA + (size_t)i * 8 * 16384 + kt, As + (wid * 16 + i * 8) * 128);
                async16(gB + (size_t)i * 8 * 16384 + kt, Bs + (wid * 16 + i * 8) * 128);
            }
        }
        const signed char* As = smem + (it & 1) * 32768;
        const signed char* Bs = As + 16384;
        #pragma unroll
        for (int ks = 0; ks < 2; ks++) {
            int sw = (((ks * 4) + (l >> 4)) ^ (l & 7)) * 16;
            v4i af[2], bf[4];
            #pragma unroll
            for (int i = 0; i < 2; i++)
                af[i] = *(const v4i*)&As[(wn0 + i * 16 + (l & 15)) * 128 + sw];
            #pragma unroll
            for (int q = 0; q < 4; q++)
                bf[q] = *(const v4i*)&Bs[(wj0 + q * 16 + (l & 15)) * 128 + sw];
            #pragma unroll
            for (int i = 0; i < 2; i++)
                #pragma unroll
                for (int q = 0; q < 4; q++)
                    acc[i][q] = __builtin_amdgcn_mfma_i32_16x16x64_i8(af[i], bf[q], acc[i][q], 0, 0, 0);
        }
    }

    __syncthreads();
    int* S = (int*)smem;
    #pragma unroll
    for (int i = 0; i < 2; i++)
        #pragma unroll
        for (int q = 0; q < 4; q++)
            #pragma unroll
            for (int rr = 0; rr < 4; rr++) {
                int n_l  = wn0 + i * 16 + (l >> 4) * 4 + rr;
                int jm_l = wj0 + q * 16 + (l & 15);
                S[n_l * 128 + jm_l] = acc[i][q][rr];
            }
    __syncthreads();

    const double SCALE = 1.0 / 4294967296.0;
    #pragma unroll
    for (int i = 0; i < 8; i++) {
        int idx = t * 8 + i;
        int n_l = idx >> 5, j_l = idx & 31;
        int4 s = *(const int4*)&S[n_l * 128 + j_l * 4];
        double val = (double)s.x + 128.0 * (double)s.y
                   + 16384.0 * (double)s.z + 2097152.0 * (double)s.w;
        int j = blockIdx.x * 32 + j_l;
        double p = val * SCALE + (double)fc1b[j];
        hs[(size_t)(nb0 + n_l) * 1024 + j] = (signed char)((p > 0.0) - (p < 0.0));
    }
}

// -------- Kernel 5: fc2, thread per (n,m) output, fp64 accumulate.
__global__ void k5_fc2(const signed char* __restrict__ hs,
                       const float* __restrict__ fc2w, const float* __restrict__ fc2b,
                       float* __restrict__ out)
{
    int idx = blockIdx.x * 64 + threadIdx.x;
    if (idx >= 10240) return;
    int n = idx / 10, m = idx - n * 10;
    const signed char* hr = hs + (size_t)n * 1024;
    const float* wr = fc2w + (size_t)m * 1024;
    double acc = (double)fc2b[m];
    for (int jb = 0; jb < 1024; jb += 16) {
        int4 hv = *(const int4*)(hr + jb);
        int wd[4] = {hv.x, hv.y, hv.z, hv.w};
        #pragma unroll
        for (int u = 0; u < 4; u++)
            #pragma unroll
            for (int e = 0; e < 4; e++)
                acc += (double)(signed char)(wd[u] >> (8 * e)) * (double)wr[jb + u * 4 + e];
    }
    out[idx] = (float)acc;
}

extern "C" void kernel_launch(void* const* d_in, const int* in_sizes, int n_in,
                              void* d_out, int out_size, void* d_ws, size_t ws_size,
                              hipStream_t stream)
{
    const float* x    = (const float*)d_in[0];
    const float* w1dw = (const float*)d_in[1];
    const float* b1dw = (const float*)d_in[2];
    const float* w1pw = (const float*)d_in[3];
    const float* b1pw = (const float*)d_in[4];
    const float* w2dw = (const float*)d_in[5];
    const float* b2dw = (const float*)d_in[6];
    const float* w2pw = (const float*)d_in[7];
    const float* b2pw = (const float*)d_in[8];
    const float* fc1w = (const float*)d_in[9];
    const float* fc1b = (const float*)d_in[10];
    const float* fc2w = (const float*)d_in[11];
    const float* fc2b = (const float*)d_in[12];
    float* out = (float*)d_out;

    char* ws = (char*)d_ws;
    signed char* pooled1T = (signed char*)(ws);
    signed char* hT2      = (signed char*)(ws + 67108864);
    signed char* w2s      = (signed char*)(ws + 83886080);
    int*         b2adj    = (int*)(ws + 83886080 + 32768);
    signed char* BL       = (signed char*)(ws);
    signed char* hs       = (signed char*)(ws + 83886080);

    hipLaunchKernelGGL(k1_conv1,  dim3(1024),  dim3(256), 0, stream,
                       x, w1dw, b1dw, w1pw, b1pw, pooled1T);
    hipLaunchKernelGGL(kprep2,    dim3(4),     dim3(64),  0, stream,
                       w2pw, b2pw, w2s, b2adj);
    hipLaunchKernelGGL(k3_fused,  dim3(1024),  dim3(256), 0, stream,
                       pooled1T, w2dw, b2dw, w2s, b2adj, hT2);
    hipLaunchKernelGGL(kprep,     dim3(16384), dim3(256), 0, stream,
                       fc1w, BL);
    hipLaunchKernelGGL(k4_fc1_mfma, dim3(32, 8), dim3(512), 0, stream,
                       hT2, BL, fc1b, hs);
    hipLaunchKernelGGL(k5_fc2,    dim3(160),   dim3(64),  0, stream,
                       hs, fc2w, fc2b, out);
}

// Round 8
// 320.195 us; speedup vs baseline: 8.9644x; 1.1656x over previous
//
#include <hip/hip_runtime.h>

// BinaryConnectNet forward.
// R8: k4 rebuilt — 4 waves x (64x64) wave-tiles (0.5 KB LDS-read/MFMA) and
// K-split x2 (512 blocks = 2/CU) with exact fp64 partials + combine kernel,
// gated on ws_size (fallback = R7 k4). k1 o-loop via 16-entry pattern table.

__device__ __forceinline__ int fsign(float v)  { return (v > 0.f) - (v < 0.f); }
__device__ __forceinline__ int dsign(double v) { return (v > 0.0) - (v < 0.0); }

typedef int v4i __attribute__((ext_vector_type(4)));

__device__ __forceinline__ void async16(const signed char* g, signed char* l) {
    __builtin_amdgcn_global_load_lds(
        (const __attribute__((address_space(1))) void*)g,
        (__attribute__((address_space(3))) void*)l, 16, 0, 0);
}

// -------- Kernel 1: conv1 dw(3x3,g=3) + pw(1x1 3->128) + sign + maxpool2
// -> pooled1T [n][y16][x16][c128] int8. o-loop via per-thread 16-entry table:
// sign patterns of (w1pw row, b1pw) -> precomputed max-sign over 4 sub-positions.
__global__ void k1_conv1(const float* __restrict__ x,
                         const float* __restrict__ w1dw, const float* __restrict__ b1dw,
                         const float* __restrict__ w1pw, const float* __restrict__ b1pw,
                         signed char* __restrict__ pooled1T)
{
    __shared__ float sdw[27], sbdw[3];
    __shared__ unsigned char spidx[128];
    int t = threadIdx.x;
    if (t < 27) sdw[t] = (float)fsign(w1dw[t]);
    if (t < 3)  sbdw[t] = (float)fsign(b1dw[t]);
    if (t < 128) {
        int b0 = w1pw[t * 3 + 0] > 0.f;
        int b1 = w1pw[t * 3 + 1] > 0.f;
        int b2 = w1pw[t * 3 + 2] > 0.f;
        int b3 = b1pw[t] > 0.f;
        spidx[t] = (unsigned char)(b0 | (b1 << 1) | (b2 << 2) | (b3 << 3));
    }
    __syncthreads();

    int g  = blockIdx.x * 256 + t;
    int px = g & 15, py = (g >> 4) & 15, n = g >> 8;

    double h[3][4];
    const float* xb = x + (size_t)n * 3 * 1024;
    #pragma unroll
    for (int c = 0; c < 3; c++) {
        const float* xc = xb + c * 1024;
        #pragma unroll
        for (int dy = 0; dy < 2; dy++)
        #pragma unroll
        for (int dx = 0; dx < 2; dx++) {
            int y = 2 * py + dy, xx = 2 * px + dx;
            double acc = (double)sbdw[c];
            #pragma unroll
            for (int ky = 0; ky < 3; ky++) {
                int yy = y + ky - 1;
                if (yy < 0 || yy > 31) continue;
                #pragma unroll
                for (int kx = 0; kx < 3; kx++) {
                    int xxx = xx + kx - 1;
                    if (xxx < 0 || xxx > 31) continue;
                    acc += (double)sdw[c * 9 + ky * 3 + kx] * (double)xc[yy * 32 + xxx];
                }
            }
            h[c][dy * 2 + dx] = acc;
        }
    }

    // butterfly: t(s0,s1,s2) for base patterns b0=1; negation covers b0=0.
    // bp: 0->(+,-,-) pat1, 1->(+,+,-) pat3, 2->(+,-,+) pat5, 3->(+,+,+) pat7
    double tv[4][4];
    #pragma unroll
    for (int q = 0; q < 4; q++) {
        double u = h[0][q] + h[1][q];
        double v = h[0][q] - h[1][q];
        tv[0][q] = v - h[2][q];
        tv[1][q] = u - h[2][q];
        tv[2][q] = v + h[2][q];
        tv[3][q] = u + h[2][q];
    }
    int mpack = 0;
    #pragma unroll
    for (int bp = 0; bp < 4; bp++) {
        int mxP = -2, mnP = 2, mxM = -2, mnM = 2;
        #pragma unroll
        for (int q = 0; q < 4; q++) {
            int sP = dsign(tv[bp][q] + 1.0);
            int sM = dsign(tv[bp][q] - 1.0);
            mxP = max(mxP, sP); mnP = min(mnP, sP);
            mxM = max(mxM, sM); mnM = min(mnM, sM);
        }
        int pat1 = 1 | (bp << 1);          // b0=1 pattern index (bits b0,b1,b2)
        int pat0 = (~pat1) & 7;            // all signs flipped
        mpack |= (mxP + 1)   << (2 * (pat1 | 8));   // sb=+1
        mpack |= (mxM + 1)   << (2 * pat1);         // sb=-1
        mpack |= ((-mnM) + 1) << (2 * (pat0 | 8));  // flipped, sb=+1
        mpack |= ((-mnP) + 1) << (2 * pat0);        // flipped, sb=-1
    }

    signed char* outb = pooled1T + (size_t)n * 32768 + (py * 16 + px) * 128;
    const int* pint = (const int*)spidx;
    for (int ob = 0; ob < 32; ob++) {
        int pw = pint[ob];
        int cur = 0;
        #pragma unroll
        for (int e = 0; e < 4; e++) {
            int pi = (pw >> (8 * e)) & 15;
            int mv = ((mpack >> (pi * 2)) & 3) - 1;
            cur |= (mv & 0xff) << (8 * e);
        }
        *(int*)(outb + ob * 4) = cur;
    }
}

// -------- Prep: conv2-pw sign matrix + adjusted bias b2adj[o] = sign(b)-32*rowsum.
__global__ void kprep2(const float* __restrict__ w2pw, const float* __restrict__ b2pw,
                       signed char* __restrict__ w2s, int* __restrict__ b2adj)
{
    int o = blockIdx.x * 64 + threadIdx.x;   // 256
    int rs = 0;
    for (int cq = 0; cq < 32; cq++) {
        float4 w = *(const float4*)(w2pw + (size_t)o * 128 + cq * 4);
        int s0 = fsign(w.x), s1 = fsign(w.y), s2 = fsign(w.z), s3 = fsign(w.w);
        rs += s0 + s1 + s2 + s3;
        int pk = (s0 & 0xff) | ((s1 & 0xff) << 8) | ((s2 & 0xff) << 16) | ((s3 & 0xff) << 24);
        *(int*)(w2s + (size_t)o * 128 + cq * 4) = pk;
    }
    b2adj[o] = fsign(b2pw[o]) - 32 * rs;
}

// -------- Kernel 3 (fused): depthwise conv2 + pointwise MFMA GEMM + sign + maxpool
// -> hT2 [n][16384]. Pooled sample staged in LDS (XOR-swizzled 16B chunks).
__global__ __launch_bounds__(256, 3) void k3_fused(
    const signed char* __restrict__ pooled1T,
    const float* __restrict__ w2dw, const float* __restrict__ b2dw,
    const signed char* __restrict__ w2s, const int* __restrict__ b2adj,
    signed char* __restrict__ hT2)
{
    __shared__ __align__(16) signed char Ps[32768];
    __shared__ __align__(16) signed char sw4[1152];
    __shared__ __align__(16) signed char sdb2[128];
    __shared__ int sb2adj[256];
    __shared__ __align__(16) signed char Os[64 * 80];

    int t = threadIdx.x, l = t & 63, wid = t >> 6;
    int n = blockIdx.x;
    const signed char* pb = pooled1T + (size_t)n * 32768;

    #pragma unroll
    for (int it = 0; it < 8; it++) {
        int off = it * 4096 + t * 16;
        int p = off >> 7, seg = (off >> 4) & 7;
        *(int4*)&Ps[p * 128 + ((seg ^ (p & 7)) * 16)] = *(const int4*)(pb + off);
    }
    for (int i = t; i < 1152; i += 256) {
        int c = i & 127, tap = i >> 7;
        sw4[tap * 128 + c] = (signed char)fsign(w2dw[c * 9 + tap]);
    }
    if (t < 128) sdb2[t] = (signed char)(fsign(b2dw[t]) + 1);
    if (t < 256) sb2adj[t] = b2adj[t];
    __syncthreads();

    int frow = l & 15;

    v4i af[4][2];
    #pragma unroll
    for (int ks = 0; ks < 2; ks++) {
        int c0 = ks * 64 + (l >> 4) * 16;
        int cc = c0 >> 4;
        int4 w4[9];
        #pragma unroll
        for (int tap = 0; tap < 9; tap++)
            w4[tap] = *(const int4*)&sw4[tap * 128 + c0];
        int4 sdbv = *(const int4*)&sdb2[c0];

        #pragma unroll
        for (int i = 0; i < 4; i++) {
            int r = (wid * 4 + i) * 16 + frow;
            int py = r >> 5, px2 = (r >> 2) & 7, dy = (r >> 1) & 1, dx = r & 1;
            int y = 2 * py + dy, x = 2 * px2 + dx;
            int4 cnt = (int4){0, 0, 0, 0};
            #pragma unroll
            for (int ky = 0; ky < 3; ky++) {
                int yy = y + ky - 1;
                int yc = min(max(yy, 0), 15);
                #pragma unroll
                for (int kx = 0; kx < 3; kx++) {
                    int xx2 = x + kx - 1;
                    int xc = min(max(xx2, 0), 15);
                    int inb = ((yy == yc) && (xx2 == xc)) ? 0x01010101 : 0;
                    int p = yc * 16 + xc;
                    int4 v = *(const int4*)&Ps[p * 128 + ((cc ^ (p & 7)) * 16)];
                    int4 w = w4[ky * 3 + kx];
                    cnt.x += ((v.x ^ w.x) >> 1) & inb;
                    cnt.y += ((v.y ^ w.y) >> 1) & inb;
                    cnt.z += ((v.z ^ w.z) >> 1) & inb;
                    cnt.w += ((v.w ^ w.w) >> 1) & inb;
                }
            }
            int valid = (1 + (y > 0) + (y < 15)) * (1 + (x > 0) + (x < 15));
            int mb = (valid + 31) * 0x01010101;
            int4 u;
            u.x = sdbv.x + mb - (cnt.x + cnt.x);
            u.y = sdbv.y + mb - (cnt.y + cnt.y);
            u.z = sdbv.z + mb - (cnt.z + cnt.z);
            u.w = sdbv.w + mb - (cnt.w + cnt.w);
            af[i][ks] = (v4i){u.x, u.y, u.z, u.w};
        }
    }

    for (int oc = 0; oc < 4; oc++) {
        v4i acc[4][4];
        #pragma unroll
        for (int i = 0; i < 4; i++)
            #pragma unroll
            for (int jt = 0; jt < 4; jt++) acc[i][jt] = (v4i){0, 0, 0, 0};

        #pragma unroll
        for (int ks = 0; ks < 2; ks++) {
            v4i bf[4];
            #pragma unroll
            for (int jt = 0; jt < 4; jt++)
                bf[jt] = *(const v4i*)(w2s + (size_t)(oc * 64 + jt * 16 + frow) * 128
                                       + ks * 64 + (l >> 4) * 16);
            #pragma unroll
            for (int i = 0; i < 4; i++)
                #pragma unroll
                for (int jt = 0; jt < 4; jt++)
                    acc[i][jt] = __builtin_amdgcn_mfma_i32_16x16x64_i8(af[i][ks], bf[jt], acc[i][jt], 0, 0, 0);
        }

        __syncthreads();
        #pragma unroll
        for (int jt = 0; jt < 4; jt++) {
            int o_l = jt * 16 + frow;
            int bia = sb2adj[oc * 64 + o_l];
            #pragma unroll
            for (int i = 0; i < 4; i++) {
                int mx = -2;
                #pragma unroll
                for (int rr = 0; rr < 4; rr++) {
                    int p = acc[i][jt][rr] + bia;
                    int s = (p > 0) - (p < 0);
                    mx = s > mx ? s : mx;
                }
                int pp = (wid * 4 + i) * 4 + (l >> 4);
                Os[o_l * 80 + pp] = (signed char)mx;
            }
        }
        __syncthreads();
        *(int4*)&hT2[(size_t)n * 16384 + oc * 4096 + t * 16]
            = *(const int4*)&Os[(t >> 2) * 80 + (t & 3) * 16];
    }
}

// -------- Prep: fc1_w -> 4 signed radix-128 int8 limbs on 2^-32 grid (exact).
__global__ void kprep(const float* __restrict__ fc1w, signed char* __restrict__ BL)
{
    int t = threadIdx.x;
    int b = blockIdx.x;
    int j = b >> 4, kb = b & 15;
    int k0 = kb * 1024 + t * 4;
    float4 w = *(const float4*)(fc1w + (size_t)j * 16384 + k0);
    float we[4] = {w.x, w.y, w.z, w.w};
    int out[4] = {0, 0, 0, 0};
    #pragma unroll
    for (int e = 0; e < 4; e++) {
        int q = (int)rint((double)we[e] * 4294967296.0);
        q = min(max(q, -266338304), 266338304);
        int d0 = ((q + 64) & 127) - 64; q = (q - d0) >> 7;
        int d1 = ((q + 64) & 127) - 64; q = (q - d1) >> 7;
        int d2 = ((q + 64) & 127) - 64; q = (q - d2) >> 7;
        int d3 = q;
        out[0] |= (d0 & 0xff) << (8 * e);
        out[1] |= (d1 & 0xff) << (8 * e);
        out[2] |= (d2 & 0xff) << (8 * e);
        out[3] |= (d3 & 0xff) << (8 * e);
    }
    #pragma unroll
    for (int m = 0; m < 4; m++)
        *(int*)(BL + (size_t)(j * 4 + m) * 16384 + k0) = out[m];
}

// -------- Kernel 4a: fc1 GEMM, K-split x2, 4 waves, 64x64 wave-tiles,
// double-buffered global_load_lds, XOR-swizzled LDS. fp64 partials (exact).
__global__ __launch_bounds__(256, 2) void k4a_fc1(
    const signed char* __restrict__ hT2, const signed char* __restrict__ BL,
    double* __restrict__ Pd)
{
    __shared__ __align__(16) signed char smem[65536];
    int t = threadIdx.x, l = t & 63, wid = t >> 6;
    int nb0 = blockIdx.y * 128, jb0 = blockIdx.x * 128;
    int kh = blockIdx.z, k0 = kh * 8192;
    int wn0 = (wid >> 1) * 64, wj0 = (wid & 1) * 64;

    int srow = l >> 3;
    int sseg = ((l & 7) ^ srow) * 16;
    const signed char* gA = hT2 + (size_t)(nb0 + wid * 32 + srow) * 16384 + k0 + sseg;
    const signed char* gB = BL  + (size_t)(jb0 + wid * 32 + srow) * 16384 + k0 + sseg;

    v4i acc[4][4];
    #pragma unroll
    for (int i = 0; i < 4; i++)
        #pragma unroll
        for (int q = 0; q < 4; q++) acc[i][q] = (v4i){0, 0, 0, 0};

    {
        signed char* As = smem;
        signed char* Bs = smem + 16384;
        #pragma unroll
        for (int i = 0; i < 4; i++) {
            async16(gA + (size_t)i * 8 * 16384, As + (wid * 32 + i * 8) * 128);
            async16(gB + (size_t)i * 8 * 16384, Bs + (wid * 32 + i * 8) * 128);
        }
    }

    for (int it = 0; it < 64; it++) {
        __syncthreads();
        if (it + 1 < 64) {
            int kt = (it + 1) * 128;
            signed char* As = smem + ((it + 1) & 1) * 32768;
            signed char* Bs = As + 16384;
            #pragma unroll
            for (int i = 0; i < 4; i++) {
                async16(gA + (size_t)i * 8 * 16384 + kt, As + (wid * 32 + i * 8) * 128);
                async16(gB + (size_t)i * 8 * 16384 + kt, Bs + (wid * 32 + i * 8) * 128);
            }
        }
        const signed char* As = smem + (it & 1) * 32768;
        const signed char* Bs = As + 16384;
        #pragma unroll
        for (int ks = 0; ks < 2; ks++) {
            int sw = (((ks * 4) + (l >> 4)) ^ (l & 7)) * 16;
            v4i af[4], bf[4];
            #pragma unroll
            for (int i = 0; i < 4; i++)
                af[i] = *(const v4i*)&As[(wn0 + i * 16 + (l & 15)) * 128 + sw];
            #pragma unroll
            for (int q = 0; q < 4; q++)
                bf[q] = *(const v4i*)&Bs[(wj0 + q * 16 + (l & 15)) * 128 + sw];
            #pragma unroll
            for (int i = 0; i < 4; i++)
                #pragma unroll
                for (int q = 0; q < 4; q++)
                    acc[i][q] = __builtin_amdgcn_mfma_i32_16x16x64_i8(af[i], bf[q], acc[i][q], 0, 0, 0);
        }
    }

    __syncthreads();
    int* S = (int*)smem;    // [128 n][128 jm]
    #pragma unroll
    for (int i = 0; i < 4; i++)
        #pragma unroll
        for (int q = 0; q < 4; q++)
            #pragma unroll
            for (int rr = 0; rr < 4; rr++) {
                int n_l  = wn0 + i * 16 + (l >> 4) * 4 + rr;
                int jm_l = wj0 + q * 16 + (l & 15);
                S[n_l * 128 + jm_l] = acc[i][q][rr];
            }
    __syncthreads();

    #pragma unroll
    for (int e = 0; e < 16; e++) {
        int idx = t * 16 + e;                 // 4096 = 128 n x 32 j
        int n_l = idx >> 5, j_l = idx & 31;
        int4 s = *(const int4*)&S[n_l * 128 + j_l * 4];
        double val = (double)s.x + 128.0 * (double)s.y
                   + 16384.0 * (double)s.z + 2097152.0 * (double)s.w;
        Pd[(size_t)kh * 1048576 + (size_t)(nb0 + n_l) * 1024 + blockIdx.x * 32 + j_l] = val;
    }
}

// -------- Kernel 4b: combine K-halves + bias + sign -> hs.
__global__ void k4b_comb(const double* __restrict__ Pd, const float* __restrict__ fc1b,
                         signed char* __restrict__ hs)
{
    int g = blockIdx.x * 256 + threadIdx.x;   // 262144
    int n = g >> 8, j0 = (g & 255) * 4;
    const double SCALE = 1.0 / 4294967296.0;
    int outv = 0;
    #pragma unroll
    for (int e = 0; e < 4; e++) {
        int j = j0 + e;
        double v = Pd[(size_t)n * 1024 + j] + Pd[1048576 + (size_t)n * 1024 + j];
        double p = v * SCALE + (double)fc1b[j];
        outv |= (dsign(p) & 0xff) << (8 * e);
    }
    *(int*)(hs + (size_t)n * 1024 + j0) = outv;
}

// -------- Kernel 4 (fallback, R7): 512 thr, dbuf, swizzled. Used if ws too small.
__global__ __launch_bounds__(512) void k4_fc1_mfma(
    const signed char* __restrict__ hT2, const signed char* __restrict__ BL,
    const float* __restrict__ fc1b, signed char* __restrict__ hs)
{
    __shared__ __align__(16) signed char smem[65536];
    int t = threadIdx.x, l = t & 63, wid = t >> 6;
    int nb0 = blockIdx.y * 128, jb0 = blockIdx.x * 128;
    int wn0 = (wid >> 1) * 32;
    int wj0 = (wid & 1) * 64;

    int srow = l >> 3;
    int sseg = ((l & 7) ^ srow) * 16;
    const signed char* gA = hT2 + (size_t)(nb0 + wid * 16 + srow) * 16384 + sseg;
    const signed char* gB = BL  + (size_t)(jb0 + wid * 16 + srow) * 16384 + sseg;

    v4i acc[2][4];
    #pragma unroll
    for (int i = 0; i < 2; i++)
        #pragma unroll
        for (int q = 0; q < 4; q++) acc[i][q] = (v4i){0, 0, 0, 0};

    {
        signed char* As = smem;
        signed char* Bs = smem + 16384;
        #pragma unroll
        for (int i = 0; i < 2; i++) {
            async16(gA + (size_t)i * 8 * 16384, As + (wid * 16 + i * 8) * 128);
            async16(gB + (size_t)i * 8 * 16384, Bs + (wid * 16 + i * 8) * 128);
        }
    }

    for (int it = 0; it < 128; it++) {
        __syncthreads();
        if (it + 1 < 128) {
            int kt = (it + 1) * 128;
            signed char* As = smem + ((it + 1) & 1) * 32768;
            signed char* Bs = As + 16384;
            #pragma unroll
            for (int i = 0; i < 2; i++) {
                async16(gA + (size_t)i * 8 * 16384 + kt, As + (wid * 16 + i * 8) * 128);
                async16(gB + (size_t)i * 8 * 16384 + kt, Bs + (wid * 16 + i * 8) * 128);
            }
        }
        const signed char* As = smem + (it & 1) * 32768;
        const signed char* Bs = As + 16384;
        #pragma unroll
        for (int ks = 0; ks < 2; ks++) {
            int sw = (((ks * 4) + (l >> 4)) ^ (l & 7)) * 16;
            v4i af[2], bf[4];
            #pragma unroll
            for (int i = 0; i < 2; i++)
                af[i] = *(const v4i*)&As[(wn0 + i * 16 + (l & 15)) * 128 + sw];
            #pragma unroll
            for (int q = 0; q < 4; q++)
                bf[q] = *(const v4i*)&Bs[(wj0 + q * 16 + (l & 15)) * 128 + sw];
            #pragma unroll
            for (int i = 0; i < 2; i++)
                #pragma unroll
                for (int q = 0; q < 4; q++)
                    acc[i][q] = __builtin_amdgcn_mfma_i32_16x16x64_i8(af[i], bf[q], acc[i][q], 0, 0, 0);
        }
    }

    __syncthreads();
    int* S = (int*)smem;
    #pragma unroll
    for (int i = 0; i < 2; i++)
        #pragma unroll
        for (int q = 0; q < 4; q++)
            #pragma unroll
            for (int rr = 0; rr < 4; rr++) {
                int n_l  = wn0 + i * 16 + (l >> 4) * 4 + rr;
                int jm_l = wj0 + q * 16 + (l & 15);
                S[n_l * 128 + jm_l] = acc[i][q][rr];
            }
    __syncthreads();

    const double SCALE = 1.0 / 4294967296.0;
    #pragma unroll
    for (int i = 0; i < 8; i++) {
        int idx = t * 8 + i;
        int n_l = idx >> 5, j_l = idx & 31;
        int4 s = *(const int4*)&S[n_l * 128 + j_l * 4];
        double val = (double)s.x + 128.0 * (double)s.y
                   + 16384.0 * (double)s.z + 2097152.0 * (double)s.w;
        int j = blockIdx.x * 32 + j_l;
        double p = val * SCALE + (double)fc1b[j];
        hs[(size_t)(nb0 + n_l) * 1024 + j] = (signed char)((p > 0.0) - (p < 0.0));
    }
}

// -------- Kernel 5: fc2, thread per (n,m) output, fp64 accumulate.
__global__ void k5_fc2(const signed char* __restrict__ hs,
                       const float* __restrict__ fc2w, const float* __restrict__ fc2b,
                       float* __restrict__ out)
{
    int idx = blockIdx.x * 64 + threadIdx.x;
    if (idx >= 10240) return;
    int n = idx / 10, m = idx - n * 10;
    const signed char* hr = hs + (size_t)n * 1024;
    const float* wr = fc2w + (size_t)m * 1024;
    double acc = (double)fc2b[m];
    for (int jb = 0; jb < 1024; jb += 16) {
        int4 hv = *(const int4*)(hr + jb);
        int wd[4] = {hv.x, hv.y, hv.z, hv.w};
        #pragma unroll
        for (int u = 0; u < 4; u++)
            #pragma unroll
            for (int e = 0; e < 4; e++)
                acc += (double)(signed char)(wd[u] >> (8 * e)) * (double)wr[jb + u * 4 + e];
    }
    out[idx] = (float)acc;
}

extern "C" void kernel_launch(void* const* d_in, const int* in_sizes, int n_in,
                              void* d_out, int out_size, void* d_ws, size_t ws_size,
                              hipStream_t stream)
{
    const float* x    = (const float*)d_in[0];
    const float* w1dw = (const float*)d_in[1];
    const float* b1dw = (const float*)d_in[2];
    const float* w1pw = (const float*)d_in[3];
    const float* b1pw = (const float*)d_in[4];
    const float* w2dw = (const float*)d_in[5];
    const float* b2dw = (const float*)d_in[6];
    const float* w2pw = (const float*)d_in[7];
    const float* b2pw = (const float*)d_in[8];
    const float* fc1w = (const float*)d_in[9];
    const float* fc1b = (const float*)d_in[10];
    const float* fc2w = (const float*)d_in[11];
    const float* fc2b = (const float*)d_in[12];
    float* out = (float*)d_out;

    // workspace:
    //   pooled1T @0        33.5MB  (dead after k3_fused)
    //   BL       @0        64MiB   (written by kprep after k3_fused)
    //   hT2      @64MiB    16MiB
    //   w2s/b2adj@80MiB    33KB    (dead after k3_fused; region reused as hs)
    //   hs       @80MiB    1MiB
    //   Pd       @84934656 16MiB   fp64 K-split partials (only if ws allows)
    char* ws = (char*)d_ws;
    signed char* pooled1T = (signed char*)(ws);
    signed char* hT2      = (signed char*)(ws + 67108864);
    signed char* w2s      = (signed char*)(ws + 83886080);
    int*         b2adj    = (int*)(ws + 83886080 + 32768);
    signed char* BL       = (signed char*)(ws);
    signed char* hs       = (signed char*)(ws + 83886080);
    double*      Pd       = (double*)(ws + 84934656);
    bool split = ws_size >= (size_t)84934656 + 16777216;

    hipLaunchKernelGGL(k1_conv1,  dim3(1024),  dim3(256), 0, stream,
                       x, w1dw, b1dw, w1pw, b1pw, pooled1T);
    hipLaunchKernelGGL(kprep2,    dim3(4),     dim3(64),  0, stream,
                       w2pw, b2pw, w2s, b2adj);
    hipLaunchKernelGGL(k3_fused,  dim3(1024),  dim3(256), 0, stream,
                       pooled1T, w2dw, b2dw, w2s, b2adj, hT2);
    hipLaunchKernelGGL(kprep,     dim3(16384), dim3(256), 0, stream,
                       fc1w, BL);
    if (split) {
        hipLaunchKernelGGL(k4a_fc1,  dim3(32, 8, 2), dim3(256), 0, stream,
                           hT2, BL, Pd);
        hipLaunchKernelGGL(k4b_comb, dim3(1024),     dim3(256), 0, stream,
                           Pd, fc1b, hs);
    } else {
        hipLaunchKernelGGL(k4_fc1_mfma, dim3(32, 8), dim3(512), 0, stream,
                           hT2, BL, fc1b, hs);
    }
    hipLaunchKernelGGL(k5_fc2,    dim3(160),   dim3(64),  0, stream,
                       hs, fc2w, fc2b, out);
}

// Round 9
// 298.342 us; speedup vs baseline: 9.6210x; 1.0732x over previous
//
#include <hip/hip_runtime.h>

// BinaryConnectNet forward.
// R9: k4a = 512 thr, K-phase-split waves (0-3 even 64B half, 4-7 odd) with
// exact i32 LDS combine -> 16 waves/CU. k4b+k5 merged into k45. Math exact.

__device__ __forceinline__ int fsign(float v)  { return (v > 0.f) - (v < 0.f); }
__device__ __forceinline__ int dsign(double v) { return (v > 0.0) - (v < 0.0); }

typedef int v4i __attribute__((ext_vector_type(4)));

__device__ __forceinline__ void async16(const signed char* g, signed char* l) {
    __builtin_amdgcn_global_load_lds(
        (const __attribute__((address_space(1))) void*)g,
        (__attribute__((address_space(3))) void*)l, 16, 0, 0);
}

// -------- Kernel 1: conv1 dw(3x3,g=3) + pw(1x1 3->128) + sign + maxpool2
// -> pooled1T [n][y16][x16][c128] int8. o-loop via 16-entry pattern table.
__global__ void k1_conv1(const float* __restrict__ x,
                         const float* __restrict__ w1dw, const float* __restrict__ b1dw,
                         const float* __restrict__ w1pw, const float* __restrict__ b1pw,
                         signed char* __restrict__ pooled1T)
{
    __shared__ float sdw[27], sbdw[3];
    __shared__ unsigned char spidx[128];
    int t = threadIdx.x;
    if (t < 27) sdw[t] = (float)fsign(w1dw[t]);
    if (t < 3)  sbdw[t] = (float)fsign(b1dw[t]);
    if (t < 128) {
        int b0 = w1pw[t * 3 + 0] > 0.f;
        int b1 = w1pw[t * 3 + 1] > 0.f;
        int b2 = w1pw[t * 3 + 2] > 0.f;
        int b3 = b1pw[t] > 0.f;
        spidx[t] = (unsigned char)(b0 | (b1 << 1) | (b2 << 2) | (b3 << 3));
    }
    __syncthreads();

    int g  = blockIdx.x * 256 + t;
    int px = g & 15, py = (g >> 4) & 15, n = g >> 8;

    double h[3][4];
    const float* xb = x + (size_t)n * 3 * 1024;
    #pragma unroll
    for (int c = 0; c < 3; c++) {
        const float* xc = xb + c * 1024;
        #pragma unroll
        for (int dy = 0; dy < 2; dy++)
        #pragma unroll
        for (int dx = 0; dx < 2; dx++) {
            int y = 2 * py + dy, xx = 2 * px + dx;
            double acc = (double)sbdw[c];
            #pragma unroll
            for (int ky = 0; ky < 3; ky++) {
                int yy = y + ky - 1;
                if (yy < 0 || yy > 31) continue;
                #pragma unroll
                for (int kx = 0; kx < 3; kx++) {
                    int xxx = xx + kx - 1;
                    if (xxx < 0 || xxx > 31) continue;
                    acc += (double)sdw[c * 9 + ky * 3 + kx] * (double)xc[yy * 32 + xxx];
                }
            }
            h[c][dy * 2 + dx] = acc;
        }
    }

    double tv[4][4];
    #pragma unroll
    for (int q = 0; q < 4; q++) {
        double u = h[0][q] + h[1][q];
        double v = h[0][q] - h[1][q];
        tv[0][q] = v - h[2][q];
        tv[1][q] = u - h[2][q];
        tv[2][q] = v + h[2][q];
        tv[3][q] = u + h[2][q];
    }
    int mpack = 0;
    #pragma unroll
    for (int bp = 0; bp < 4; bp++) {
        int mxP = -2, mnP = 2, mxM = -2, mnM = 2;
        #pragma unroll
        for (int q = 0; q < 4; q++) {
            int sP = dsign(tv[bp][q] + 1.0);
            int sM = dsign(tv[bp][q] - 1.0);
            mxP = max(mxP, sP); mnP = min(mnP, sP);
            mxM = max(mxM, sM); mnM = min(mnM, sM);
        }
        int pat1 = 1 | (bp << 1);
        int pat0 = (~pat1) & 7;
        mpack |= (mxP + 1)   << (2 * (pat1 | 8));
        mpack |= (mxM + 1)   << (2 * pat1);
        mpack |= ((-mnM) + 1) << (2 * (pat0 | 8));
        mpack |= ((-mnP) + 1) << (2 * pat0);
    }

    signed char* outb = pooled1T + (size_t)n * 32768 + (py * 16 + px) * 128;
    const int* pint = (const int*)spidx;
    for (int ob = 0; ob < 32; ob++) {
        int pw = pint[ob];
        int cur = 0;
        #pragma unroll
        for (int e = 0; e < 4; e++) {
            int pi = (pw >> (8 * e)) & 15;
            int mv = ((mpack >> (pi * 2)) & 3) - 1;
            cur |= (mv & 0xff) << (8 * e);
        }
        *(int*)(outb + ob * 4) = cur;
    }
}

// -------- Prep: conv2-pw sign matrix + adjusted bias b2adj[o] = sign(b)-32*rowsum.
__global__ void kprep2(const float* __restrict__ w2pw, const float* __restrict__ b2pw,
                       signed char* __restrict__ w2s, int* __restrict__ b2adj)
{
    int o = blockIdx.x * 64 + threadIdx.x;   // 256
    int rs = 0;
    for (int cq = 0; cq < 32; cq++) {
        float4 w = *(const float4*)(w2pw + (size_t)o * 128 + cq * 4);
        int s0 = fsign(w.x), s1 = fsign(w.y), s2 = fsign(w.z), s3 = fsign(w.w);
        rs += s0 + s1 + s2 + s3;
        int pk = (s0 & 0xff) | ((s1 & 0xff) << 8) | ((s2 & 0xff) << 16) | ((s3 & 0xff) << 24);
        *(int*)(w2s + (size_t)o * 128 + cq * 4) = pk;
    }
    b2adj[o] = fsign(b2pw[o]) - 32 * rs;
}

// -------- Kernel 3 (fused): depthwise conv2 + pointwise MFMA GEMM + sign + maxpool
__global__ __launch_bounds__(256, 3) void k3_fused(
    const signed char* __restrict__ pooled1T,
    const float* __restrict__ w2dw, const float* __restrict__ b2dw,
    const signed char* __restrict__ w2s, const int* __restrict__ b2adj,
    signed char* __restrict__ hT2)
{
    __shared__ __align__(16) signed char Ps[32768];
    __shared__ __align__(16) signed char sw4[1152];
    __shared__ __align__(16) signed char sdb2[128];
    __shared__ int sb2adj[256];
    __shared__ __align__(16) signed char Os[64 * 80];

    int t = threadIdx.x, l = t & 63, wid = t >> 6;
    int n = blockIdx.x;
    const signed char* pb = pooled1T + (size_t)n * 32768;

    #pragma unroll
    for (int it = 0; it < 8; it++) {
        int off = it * 4096 + t * 16;
        int p = off >> 7, seg = (off >> 4) & 7;
        *(int4*)&Ps[p * 128 + ((seg ^ (p & 7)) * 16)] = *(const int4*)(pb + off);
    }
    for (int i = t; i < 1152; i += 256) {
        int c = i & 127, tap = i >> 7;
        sw4[tap * 128 + c] = (signed char)fsign(w2dw[c * 9 + tap]);
    }
    if (t < 128) sdb2[t] = (signed char)(fsign(b2dw[t]) + 1);
    if (t < 256) sb2adj[t] = b2adj[t];
    __syncthreads();

    int frow = l & 15;

    v4i af[4][2];
    #pragma unroll
    for (int ks = 0; ks < 2; ks++) {
        int c0 = ks * 64 + (l >> 4) * 16;
        int cc = c0 >> 4;
        int4 w4[9];
        #pragma unroll
        for (int tap = 0; tap < 9; tap++)
            w4[tap] = *(const int4*)&sw4[tap * 128 + c0];
        int4 sdbv = *(const int4*)&sdb2[c0];

        #pragma unroll
        for (int i = 0; i < 4; i++) {
            int r = (wid * 4 + i) * 16 + frow;
            int py = r >> 5, px2 = (r >> 2) & 7, dy = (r >> 1) & 1, dx = r & 1;
            int y = 2 * py + dy, x = 2 * px2 + dx;
            int4 cnt = (int4){0, 0, 0, 0};
            #pragma unroll
            for (int ky = 0; ky < 3; ky++) {
                int yy = y + ky - 1;
                int yc = min(max(yy, 0), 15);
                #pragma unroll
                for (int kx = 0; kx < 3; kx++) {
                    int xx2 = x + kx - 1;
                    int xc = min(max(xx2, 0), 15);
                    int inb = ((yy == yc) && (xx2 == xc)) ? 0x01010101 : 0;
                    int p = yc * 16 + xc;
                    int4 v = *(const int4*)&Ps[p * 128 + ((cc ^ (p & 7)) * 16)];
                    int4 w = w4[ky * 3 + kx];
                    cnt.x += ((v.x ^ w.x) >> 1) & inb;
                    cnt.y += ((v.y ^ w.y) >> 1) & inb;
                    cnt.z += ((v.z ^ w.z) >> 1) & inb;
                    cnt.w += ((v.w ^ w.w) >> 1) & inb;
                }
            }
            int valid = (1 + (y > 0) + (y < 15)) * (1 + (x > 0) + (x < 15));
            int mb = (valid + 31) * 0x01010101;
            int4 u;
            u.x = sdbv.x + mb - (cnt.x + cnt.x);
            u.y = sdbv.y + mb - (cnt.y + cnt.y);
            u.z = sdbv.z + mb - (cnt.z + cnt.z);
            u.w = sdbv.w + mb - (cnt.w + cnt.w);
            af[i][ks] = (v4i){u.x, u.y, u.z, u.w};
        }
    }

    for (int oc = 0; oc < 4; oc++) {
        v4i acc[4][4];
        #pragma unroll
        for (int i = 0; i < 4; i++)
            #pragma unroll
            for (int jt = 0; jt < 4; jt++) acc[i][jt] = (v4i){0, 0, 0, 0};

        #pragma unroll
        for (int ks = 0; ks < 2; ks++) {
            v4i bf[4];
            #pragma unroll
            for (int jt = 0; jt < 4; jt++)
                bf[jt] = *(const v4i*)(w2s + (size_t)(oc * 64 + jt * 16 + frow) * 128
                                       + ks * 64 + (l >> 4) * 16);
            #pragma unroll
            for (int i = 0; i < 4; i++)
                #pragma unroll
                for (int jt = 0; jt < 4; jt++)
                    acc[i][jt] = __builtin_amdgcn_mfma_i32_16x16x64_i8(af[i][ks], bf[jt], acc[i][jt], 0, 0, 0);
        }

        __syncthreads();
        #pragma unroll
        for (int jt = 0; jt < 4; jt++) {
            int o_l = jt * 16 + frow;
            int bia = sb2adj[oc * 64 + o_l];
            #pragma unroll
            for (int i = 0; i < 4; i++) {
                int mx = -2;
                #pragma unroll
                for (int rr = 0; rr < 4; rr++) {
                    int p = acc[i][jt][rr] + bia;
                    int s = (p > 0) - (p < 0);
                    mx = s > mx ? s : mx;
                }
                int pp = (wid * 4 + i) * 4 + (l >> 4);
                Os[o_l * 80 + pp] = (signed char)mx;
            }
        }
        __syncthreads();
        *(int4*)&hT2[(size_t)n * 16384 + oc * 4096 + t * 16]
            = *(const int4*)&Os[(t >> 2) * 80 + (t & 3) * 16];
    }
}

// -------- Prep: fc1_w -> 4 signed radix-128 int8 limbs on 2^-32 grid (exact).
__global__ void kprep(const float* __restrict__ fc1w, signed char* __restrict__ BL)
{
    int t = threadIdx.x;
    int b = blockIdx.x;
    int j = b >> 4, kb = b & 15;
    int k0 = kb * 1024 + t * 4;
    float4 w = *(const float4*)(fc1w + (size_t)j * 16384 + k0);
    float we[4] = {w.x, w.y, w.z, w.w};
    int out[4] = {0, 0, 0, 0};
    #pragma unroll
    for (int e = 0; e < 4; e++) {
        int q = (int)rint((double)we[e] * 4294967296.0);
        q = min(max(q, -266338304), 266338304);
        int d0 = ((q + 64) & 127) - 64; q = (q - d0) >> 7;
        int d1 = ((q + 64) & 127) - 64; q = (q - d1) >> 7;
        int d2 = ((q + 64) & 127) - 64; q = (q - d2) >> 7;
        int d3 = q;
        out[0] |= (d0 & 0xff) << (8 * e);
        out[1] |= (d1 & 0xff) << (8 * e);
        out[2] |= (d2 & 0xff) << (8 * e);
        out[3] |= (d3 & 0xff) << (8 * e);
    }
    #pragma unroll
    for (int m = 0; m < 4; m++)
        *(int*)(BL + (size_t)(j * 4 + m) * 16384 + k0) = out[m];
}

// -------- Kernel 4a: fc1 GEMM, K-split x2 grid + K-phase-split waves.
// 512 thr = 8 waves; waves 0-3 even 64B K-half, 4-7 odd; exact i32 combine in LDS.
__global__ __launch_bounds__(512, 4) void k4a_fc1(
    const signed char* __restrict__ hT2, const signed char* __restrict__ BL,
    double* __restrict__ Pd)
{
    __shared__ __align__(16) signed char smem[65536];
    int t = threadIdx.x, l = t & 63, wid = t >> 6;
    int nb0 = blockIdx.y * 128, jb0 = blockIdx.x * 128;
    int kh = blockIdx.z, k0 = kh * 8192;
    int ksw = wid >> 2;                       // K-phase of this wave
    int wn0 = ((wid >> 1) & 1) * 64, wj0 = (wid & 1) * 64;

    int srow = l >> 3;
    int sseg = ((l & 7) ^ srow) * 16;
    const signed char* gA = hT2 + (size_t)(nb0 + wid * 16 + srow) * 16384 + k0 + sseg;
    const signed char* gB = BL  + (size_t)(jb0 + wid * 16 + srow) * 16384 + k0 + sseg;

    v4i acc[4][4];
    #pragma unroll
    for (int i = 0; i < 4; i++)
        #pragma unroll
        for (int q = 0; q < 4; q++) acc[i][q] = (v4i){0, 0, 0, 0};

    {
        signed char* As = smem;
        signed char* Bs = smem + 16384;
        #pragma unroll
        for (int c = 0; c < 2; c++) {
            async16(gA + (size_t)c * 8 * 16384, As + (wid * 16 + c * 8) * 128);
            async16(gB + (size_t)c * 8 * 16384, Bs + (wid * 16 + c * 8) * 128);
        }
    }

    int sw = (((ksw * 4) + (l >> 4)) ^ (l & 7)) * 16;

    for (int it = 0; it < 64; it++) {
        __syncthreads();
        if (it + 1 < 64) {
            int kt = (it + 1) * 128;
            signed char* As = smem + ((it + 1) & 1) * 32768;
            signed char* Bs = As + 16384;
            #pragma unroll
            for (int c = 0; c < 2; c++) {
                async16(gA + (size_t)c * 8 * 16384 + kt, As + (wid * 16 + c * 8) * 128);
                async16(gB + (size_t)c * 8 * 16384 + kt, Bs + (wid * 16 + c * 8) * 128);
            }
        }
        const signed char* As = smem + (it & 1) * 32768;
        const signed char* Bs = As + 16384;
        v4i af[4], bf[4];
        #pragma unroll
        for (int i = 0; i < 4; i++)
            af[i] = *(const v4i*)&As[(wn0 + i * 16 + (l & 15)) * 128 + sw];
        #pragma unroll
        for (int q = 0; q < 4; q++)
            bf[q] = *(const v4i*)&Bs[(wj0 + q * 16 + (l & 15)) * 128 + sw];
        #pragma unroll
        for (int i = 0; i < 4; i++)
            #pragma unroll
            for (int q = 0; q < 4; q++)
                acc[i][q] = __builtin_amdgcn_mfma_i32_16x16x64_i8(af[i], bf[q], acc[i][q], 0, 0, 0);
    }

    __syncthreads();
    int* S = (int*)smem;    // [128 n][128 jm]
    if (ksw == 0) {
        #pragma unroll
        for (int i = 0; i < 4; i++)
            #pragma unroll
            for (int q = 0; q < 4; q++)
                #pragma unroll
                for (int rr = 0; rr < 4; rr++) {
                    int n_l  = wn0 + i * 16 + (l >> 4) * 4 + rr;
                    int jm_l = wj0 + q * 16 + (l & 15);
                    S[n_l * 128 + jm_l] = acc[i][q][rr];
                }
    }
    __syncthreads();
    if (ksw == 1) {
        #pragma unroll
        for (int i = 0; i < 4; i++)
            #pragma unroll
            for (int q = 0; q < 4; q++)
                #pragma unroll
                for (int rr = 0; rr < 4; rr++) {
                    int n_l  = wn0 + i * 16 + (l >> 4) * 4 + rr;
                    int jm_l = wj0 + q * 16 + (l & 15);
                    S[n_l * 128 + jm_l] += acc[i][q][rr];
                }
    }
    __syncthreads();

    #pragma unroll
    for (int e = 0; e < 8; e++) {
        int idx = t * 8 + e;                 // 4096 = 128 n x 32 j
        int n_l = idx >> 5, j_l = idx & 31;
        int4 s = *(const int4*)&S[n_l * 128 + j_l * 4];
        double val = (double)s.x + 128.0 * (double)s.y
                   + 16384.0 * (double)s.z + 2097152.0 * (double)s.w;
        Pd[(size_t)kh * 1048576 + (size_t)(nb0 + n_l) * 1024 + blockIdx.x * 32 + j_l] = val;
    }
}

// -------- Kernel 45: combine K-halves + bias + sign, then fc2 (block per n).
__global__ __launch_bounds__(256) void k45_comb_fc2(
    const double* __restrict__ Pd, const float* __restrict__ fc1b,
    const float* __restrict__ fc2w, const float* __restrict__ fc2b,
    float* __restrict__ out)
{
    __shared__ double sj[1024];
    __shared__ double pw[4][10];
    int t = threadIdx.x, n = blockIdx.x;
    const double SCALE = 1.0 / 4294967296.0;

    #pragma unroll
    for (int rep = 0; rep < 4; rep++) {
        int j = rep * 256 + t;
        double v = Pd[(size_t)n * 1024 + j] + Pd[1048576 + (size_t)n * 1024 + j];
        double p = v * SCALE + (double)fc1b[j];
        sj[j] = (double)((p > 0.0) - (p < 0.0));
    }
    __syncthreads();

    int j0 = t * 4;
    double s0 = sj[j0], s1 = sj[j0 + 1], s2 = sj[j0 + 2], s3 = sj[j0 + 3];
    double acc[10];
    #pragma unroll
    for (int m = 0; m < 10; m++) {
        float4 w = *(const float4*)(fc2w + (size_t)m * 1024 + j0);
        acc[m] = s0 * (double)w.x + s1 * (double)w.y + s2 * (double)w.z + s3 * (double)w.w;
    }
    #pragma unroll
    for (int off = 32; off > 0; off >>= 1)
        #pragma unroll
        for (int m = 0; m < 10; m++)
            acc[m] += __shfl_down(acc[m], off);
    if ((t & 63) == 0)
        #pragma unroll
        for (int m = 0; m < 10; m++) pw[t >> 6][m] = acc[m];
    __syncthreads();
    if (t < 10)
        out[n * 10 + t] = (float)(pw[0][t] + pw[1][t] + pw[2][t] + pw[3][t] + (double)fc2b[t]);
}

// -------- Fallback (ws too small): R7-style combined k4 + old k5 via hs.
__global__ __launch_bounds__(512) void k4_fc1_mfma(
    const signed char* __restrict__ hT2, const signed char* __restrict__ BL,
    const float* __restrict__ fc1b, signed char* __restrict__ hs)
{
    __shared__ __align__(16) signed char smem[65536];
    int t = threadIdx.x, l = t & 63, wid = t >> 6;
    int nb0 = blockIdx.y * 128, jb0 = blockIdx.x * 128;
    int wn0 = (wid >> 1) * 32;
    int wj0 = (wid & 1) * 64;

    int srow = l >> 3;
    int sseg = ((l & 7) ^ srow) * 16;
    const signed char* gA = hT2 + (size_t)(nb0 + wid * 16 + srow) * 16384 + sseg;
    const signed char* gB = BL  + (size_t)(jb0 + wid * 16 + srow) * 16384 + sseg;

    v4i acc[2][4];
    #pragma unroll
    for (int i = 0; i < 2; i++)
        #pragma unroll
        for (int q = 0; q < 4; q++) acc[i][q] = (v4i){0, 0, 0, 0};

    {
        signed char* As = smem;
        signed char* Bs = smem + 16384;
        #pragma unroll
        for (int i = 0; i < 2; i++) {
            async16(gA + (size_t)i * 8 * 16384, As + (wid * 16 + i * 8) * 128);
            async16(gB + (size_t)i * 8 * 16384, Bs + (wid * 16 + i * 8) * 128);
        }
    }

    for (int it = 0; it < 128; it++) {
        __syncthreads();
        if (it + 1 < 128) {
            int kt = (it + 1) * 128;
            signed char* As = smem + ((it + 1) & 1) * 32768;
            signed char* Bs = As + 16384;
            #pragma unroll
            for (int i = 0; i < 2; i++) {
                async16(gA + (size_t)i * 8 * 16384 + kt, As + (wid * 16 + i * 8) * 128);
                async16(gB + (size_t)i * 8 * 16384 + kt, Bs + (wid * 16 + i * 8) * 128);
            }
        }
        const signed char* As = smem + (it & 1) * 32768;
        const signed char* Bs = As + 16384;
        #pragma unroll
        for (int ks = 0; ks < 2; ks++) {
            int sw = (((ks * 4) + (l >> 4)) ^ (l & 7)) * 16;
            v4i af[2], bf[4];
            #pragma unroll
            for (int i = 0; i < 2; i++)
                af[i] = *(const v4i*)&As[(wn0 + i * 16 + (l & 15)) * 128 + sw];
            #pragma unroll
            for (int q = 0; q < 4; q++)
                bf[q] = *(const v4i*)&Bs[(wj0 + q * 16 + (l & 15)) * 128 + sw];
            #pragma unroll
            for (int i = 0; i < 2; i++)
                #pragma unroll
                for (int q = 0; q < 4; q++)
                    acc[i][q] = __builtin_amdgcn_mfma_i32_16x16x64_i8(af[i], bf[q], acc[i][q], 0, 0, 0);
        }
    }

    __syncthreads();
    int* S = (int*)smem;
    #pragma unroll
    for (int i = 0; i < 2; i++)
        #pragma unroll
        for (int q = 0; q < 4; q++)
            #pragma unroll
            for (int rr = 0; rr < 4; rr++) {
                int n_l  = wn0 + i * 16 + (l >> 4) * 4 + rr;
                int jm_l = wj0 + q * 16 + (l & 15);
                S[n_l * 128 + jm_l] = acc[i][q][rr];
            }
    __syncthreads();

    const double SCALE = 1.0 / 4294967296.0;
    #pragma unroll
    for (int i = 0; i < 8; i++) {
        int idx = t * 8 + i;
        int n_l = idx >> 5, j_l = idx & 31;
        int4 s = *(const int4*)&S[n_l * 128 + j_l * 4];
        double val = (double)s.x + 128.0 * (double)s.y
                   + 16384.0 * (double)s.z + 2097152.0 * (double)s.w;
        int j = blockIdx.x * 32 + j_l;
        double p = val * SCALE + (double)fc1b[j];
        hs[(size_t)(nb0 + n_l) * 1024 + j] = (signed char)((p > 0.0) - (p < 0.0));
    }
}

__global__ void k5_fc2(const signed char* __restrict__ hs,
                       const float* __restrict__ fc2w, const float* __restrict__ fc2b,
                       float* __restrict__ out)
{
    int idx = blockIdx.x * 64 + threadIdx.x;
    if (idx >= 10240) return;
    int n = idx / 10, m = idx - n * 10;
    const signed char* hr = hs + (size_t)n * 1024;
    const float* wr = fc2w + (size_t)m * 1024;
    double acc = (double)fc2b[m];
    for (int jb = 0; jb < 1024; jb += 16) {
        int4 hv = *(const int4*)(hr + jb);
        int wd[4] = {hv.x, hv.y, hv.z, hv.w};
        #pragma unroll
        for (int u = 0; u < 4; u++)
            #pragma unroll
            for (int e = 0; e < 4; e++)
                acc += (double)(signed char)(wd[u] >> (8 * e)) * (double)wr[jb + u * 4 + e];
    }
    out[idx] = (float)acc;
}

extern "C" void kernel_launch(void* const* d_in, const int* in_sizes, int n_in,
                              void* d_out, int out_size, void* d_ws, size_t ws_size,
                              hipStream_t stream)
{
    const float* x    = (const float*)d_in[0];
    const float* w1dw = (const float*)d_in[1];
    const float* b1dw = (const float*)d_in[2];
    const float* w1pw = (const float*)d_in[3];
    const float* b1pw = (const float*)d_in[4];
    const float* w2dw = (const float*)d_in[5];
    const float* b2dw = (const float*)d_in[6];
    const float* w2pw = (const float*)d_in[7];
    const float* b2pw = (const float*)d_in[8];
    const float* fc1w = (const float*)d_in[9];
    const float* fc1b = (const float*)d_in[10];
    const float* fc2w = (const float*)d_in[11];
    const float* fc2b = (const float*)d_in[12];
    float* out = (float*)d_out;

    // workspace:
    //   pooled1T @0        33.5MB  (dead after k3_fused)
    //   BL       @0        64MiB   (written by kprep after k3_fused)
    //   hT2      @64MiB    16MiB
    //   w2s/b2adj@80MiB    33KB    (dead after k3_fused)
    //   hs       @80MiB    1MiB    (fallback path only)
    //   Pd       @84934656 16MiB   fp64 K-split partials
    char* ws = (char*)d_ws;
    signed char* pooled1T = (signed char*)(ws);
    signed char* hT2      = (signed char*)(ws + 67108864);
    signed char* w2s      = (signed char*)(ws + 83886080);
    int*         b2adj    = (int*)(ws + 83886080 + 32768);
    signed char* BL       = (signed char*)(ws);
    signed char* hs       = (signed char*)(ws + 83886080);
    double*      Pd       = (double*)(ws + 84934656);
    bool split = ws_size >= (size_t)84934656 + 16777216;

    hipLaunchKernelGGL(k1_conv1,  dim3(1024),  dim3(256), 0, stream,
                       x, w1dw, b1dw, w1pw, b1pw, pooled1T);
    hipLaunchKernelGGL(kprep2,    dim3(4),     dim3(64),  0, stream,
                       w2pw, b2pw, w2s, b2adj);
    hipLaunchKernelGGL(k3_fused,  dim3(1024),  dim3(256), 0, stream,
                       pooled1T, w2dw, b2dw, w2s, b2adj, hT2);
    hipLaunchKernelGGL(kprep,     dim3(16384), dim3(256), 0, stream,
                       fc1w, BL);
    if (split) {
        hipLaunchKernelGGL(k4a_fc1,      dim3(32, 8, 2), dim3(512), 0, stream,
                           hT2, BL, Pd);
        hipLaunchKernelGGL(k45_comb_fc2, dim3(1024),     dim3(256), 0, stream,
                           Pd, fc1b, fc2w, fc2b, out);
    } else {
        hipLaunchKernelGGL(k4_fc1_mfma, dim3(32, 8), dim3(512), 0, stream,
                           hT2, BL, fc1b, hs);
        hipLaunchKernelGGL(k5_fc2,      dim3(160),   dim3(64),  0, stream,
                           hs, fc2w, fc2b, out);
    }
}